// Round 7
// baseline (1393.370 us; speedup 1.0000x reference)
//
#include <hip/hip_runtime.h>
#include <hip/hip_bf16.h>
#include <cstddef>

// Problem constants (Prdnet_3324304687823)
#define NN    8192
#define EE    131072
#define BB    256
#define F_AT  92
#define DD    256
#define HH    8
#define HDIM  32
#define LL    6
#define FCD   512

typedef __hip_bfloat16 bf16;
typedef __attribute__((ext_vector_type(8))) __bf16 bf16x8;
typedef __attribute__((ext_vector_type(4))) float f32x4;

__device__ __forceinline__ float to_f(float x) { return x; }
__device__ __forceinline__ float to_f(bf16 x) { return __bfloat162float(x); }
__device__ __forceinline__ float bfu(unsigned short u) {
    return __uint_as_float(((unsigned)u) << 16);
}
__device__ __forceinline__ unsigned short bfbits(float x) {
    bf16 h = __float2bfloat16(x);
    return *(unsigned short*)&h;
}
__device__ __forceinline__ void store_v(float* p, float v) { *p = v; }
__device__ __forceinline__ void store_v(bf16* p, float v) { *p = __float2bfloat16(v); }

__device__ __forceinline__ float4 load4(const float* p) { return *(const float4*)p; }
__device__ __forceinline__ float4 load4(const bf16* p) {
    const ushort4 r = *(const ushort4*)p;
    return make_float4(bfu(r.x), bfu(r.y), bfu(r.z), bfu(r.w));
}

// packed 4-element store (16 B fp32 / 8 B bf16)
__device__ __forceinline__ void store_f4(float* p, const float4& f) {
    *(float4*)p = f;
}
__device__ __forceinline__ void store_f4(bf16* p, const float4& f) {
    ushort4 u = {bfbits(f.x), bfbits(f.y), bfbits(f.z), bfbits(f.w)};
    *(ushort4*)p = u;
}

template <typename T>
__device__ __forceinline__ void load16(const T* p, float* v) {
#pragma unroll
    for (int i = 0; i < 4; ++i) {
        const float4 f = load4(p + i * 4);
        v[i * 4 + 0] = f.x; v[i * 4 + 1] = f.y;
        v[i * 4 + 2] = f.z; v[i * 4 + 3] = f.w;
    }
}

__device__ __forceinline__ bf16x8 ld8(const bf16* p) { return *(const bf16x8*)p; }
__device__ __forceinline__ bf16x8 ld8(const float* p) {
    const float4 f0 = *(const float4*)p;
    const float4 f1 = *(const float4*)(p + 4);
    bf16x8 r;
    r[0] = (__bf16)f0.x; r[1] = (__bf16)f0.y; r[2] = (__bf16)f0.z; r[3] = (__bf16)f0.w;
    r[4] = (__bf16)f1.x; r[5] = (__bf16)f1.y; r[6] = (__bf16)f1.z; r[7] = (__bf16)f1.w;
    return r;
}

// async global->LDS, 16 B per lane; LDS dest = wave-uniform base + lane*16
__device__ __forceinline__ void async_copy16(const void* g, void* l) {
    __builtin_amdgcn_global_load_lds(
        (const __attribute__((address_space(1))) unsigned int*)g,
        (__attribute__((address_space(3))) unsigned int*)l, 16, 0, 0);
}

// ---------------------------------------------------------------------------
// Batched weight transpose: out[midx][n][k] = (bf16) src[midx][k][n]
// midx: 0=rw1 1=rw2 2=rw3 3=aw2, then per layer l: 4+5l+{0:q,1:k,2:v,3:e,4:o}
// ---------------------------------------------------------------------------
__global__ __launch_bounds__(256) void transpose_weights(
    const float* __restrict__ rw1, const float* __restrict__ rw2,
    const float* __restrict__ rw3, const float* __restrict__ aw2,
    const float* __restrict__ Wq, const float* __restrict__ Wk,
    const float* __restrict__ Wv, const float* __restrict__ We,
    const float* __restrict__ Wo, __bf16* __restrict__ out)
{
    __shared__ float tile[64][65];
    const int midx = blockIdx.y;
    const float* src;
    if (midx == 0) src = rw1;
    else if (midx == 1) src = rw2;
    else if (midx == 2) src = rw3;
    else if (midx == 3) src = aw2;
    else {
        const int l = (midx - 4) / 5, s = (midx - 4) % 5;
        const float* bases[5] = {Wq, Wk, Wv, We, Wo};
        src = bases[s] + (size_t)l * 65536;
    }
    __bf16* dst = out + (size_t)midx * 65536;
    const int k0 = (blockIdx.x >> 2) * 64;
    const int n0 = (blockIdx.x & 3) * 64;
    const int c = threadIdx.x & 63;
    const int r0 = threadIdx.x >> 6;
#pragma unroll
    for (int p = 0; p < 16; ++p) {
        const int r = r0 + p * 4;
        tile[r][c] = src[(size_t)(k0 + r) * 256 + n0 + c];
    }
    __syncthreads();
#pragma unroll
    for (int p = 0; p < 16; ++p) {
        const int n = r0 + p * 4;
        dst[(size_t)(n0 + n) * 256 + k0 + c] = (__bf16)tile[c][n];
    }
}

// pack per-layer [bq|bk|bv] -> qkvb[l*768 + ...]
__global__ __launch_bounds__(256) void pack_qkv_bias(
    const float* __restrict__ bq, const float* __restrict__ bk,
    const float* __restrict__ bv, float* __restrict__ out)
{
    const int i = blockIdx.x * 256 + threadIdx.x;
    if (i >= LL * 768) return;
    const int l = i / 768, r = i % 768;
    const float* s = (r < 256) ? bq : (r < 512) ? bk : bv;
    out[i] = s[l * 256 + (r & 255)];
}

// ---------------------------------------------------------------------------
// MFMA GEMM, async staging (A bf16 only): C = A@W + bias, Wt[Nn][K] bf16.
// 128x128 tile, BK=64, 4 waves 2x2, global_load_lds width=16, unpadded LDS.
// ---------------------------------------------------------------------------
template <typename CT>
__global__ __launch_bounds__(256) void mfma_gemm_async(
    const bf16* __restrict__ A, const __bf16* __restrict__ Wt,
    const float* __restrict__ bias, CT* __restrict__ C,
    int M, int Nn, int K)
{
    __shared__ __align__(16) __bf16 As[128 * 64];
    __shared__ __align__(16) __bf16 Bs[128 * 64];
    const int tid = threadIdx.x;
    const int m0 = blockIdx.x * 128;
    const int n0 = blockIdx.y * 128;
    const int wave = tid >> 6, lane = tid & 63;
    const int wm = (wave & 1) * 64, wn = (wave >> 1) * 64;
    const int lm = lane & 15, lq = lane >> 4;
    const int lrow = lane >> 3;          // 0..7 within 8-row chunk
    const int lcol = (lane & 7) * 8;     // elem offset 0..56

    f32x4 acc[4][4] = {};

    for (int k0 = 0; k0 < K; k0 += 64) {
#pragma unroll
        for (int p = 0; p < 4; ++p) {
            const int rbase = wave * 32 + p * 8;
            async_copy16(A  + (size_t)(m0 + rbase + lrow) * K + k0 + lcol,
                         As + rbase * 64);
            async_copy16(Wt + (size_t)(n0 + rbase + lrow) * K + k0 + lcol,
                         Bs + rbase * 64);
        }
        __syncthreads();  // drains vmcnt (global_load_lds) + barrier
#pragma unroll
        for (int ks = 0; ks < 2; ++ks) {
            bf16x8 a[4], b[4];
#pragma unroll
            for (int i = 0; i < 4; ++i) {
                a[i] = *(const bf16x8*)(As + (wm + i * 16 + lm) * 64 + ks * 32 + lq * 8);
                b[i] = *(const bf16x8*)(Bs + (wn + i * 16 + lm) * 64 + ks * 32 + lq * 8);
            }
#pragma unroll
            for (int i = 0; i < 4; ++i)
#pragma unroll
                for (int j = 0; j < 4; ++j)
                    acc[i][j] = __builtin_amdgcn_mfma_f32_16x16x32_bf16(
                        a[i], b[j], acc[i][j], 0, 0, 0);
        }
        __syncthreads();
    }

    // C/D: col = lane&15, row = (lane>>4)*4 + reg
#pragma unroll
    for (int i = 0; i < 4; ++i) {
        const int gm = m0 + wm + i * 16 + lq * 4;
#pragma unroll
        for (int j = 0; j < 4; ++j) {
            const int gn = n0 + wn + j * 16 + lm;
            const float bv = bias ? bias[gn] : 0.f;
#pragma unroll
            for (int r = 0; r < 4; ++r)
                store_v(&C[(size_t)(gm + r) * Nn + gn], acc[i][j][r] + bv);
        }
    }
}

// ---------------------------------------------------------------------------
// MFMA GEMM, register staging (fp32 A): padded LDS, conflict-free.
// ---------------------------------------------------------------------------
template <typename AT, typename CT>
__global__ __launch_bounds__(256) void mfma_gemm(
    const AT* __restrict__ A, const __bf16* __restrict__ Wt,
    const float* __restrict__ bias, CT* __restrict__ C,
    int M, int Nn, int K)
{
    __shared__ __align__(16) __bf16 As[128 * 72];
    __shared__ __align__(16) __bf16 Bs[128 * 72];
    const int tid = threadIdx.x;
    const int m0 = blockIdx.x * 128;
    const int n0 = blockIdx.y * 128;
    const int wave = tid >> 6, lane = tid & 63;
    const int wm = (wave & 1) * 64, wn = (wave >> 1) * 64;
    const int lm = lane & 15, lq = lane >> 4;

    f32x4 acc[4][4] = {};

    const int srow = tid >> 3;
    const int scol = (tid & 7) * 8;

    for (int k0 = 0; k0 < K; k0 += 64) {
#pragma unroll
        for (int p = 0; p < 4; ++p) {
            const int r = srow + 32 * p;
            *(bf16x8*)(As + r * 72 + scol) = ld8(A + (size_t)(m0 + r) * K + k0 + scol);
            *(bf16x8*)(Bs + r * 72 + scol) = *(const bf16x8*)(Wt + (size_t)(n0 + r) * K + k0 + scol);
        }
        __syncthreads();
#pragma unroll
        for (int ks = 0; ks < 2; ++ks) {
            bf16x8 a[4], b[4];
#pragma unroll
            for (int i = 0; i < 4; ++i) {
                a[i] = *(const bf16x8*)(As + (wm + i * 16 + lm) * 72 + ks * 32 + lq * 8);
                b[i] = *(const bf16x8*)(Bs + (wn + i * 16 + lm) * 72 + ks * 32 + lq * 8);
            }
#pragma unroll
            for (int i = 0; i < 4; ++i)
#pragma unroll
                for (int j = 0; j < 4; ++j)
                    acc[i][j] = __builtin_amdgcn_mfma_f32_16x16x32_bf16(
                        a[i], b[j], acc[i][j], 0, 0, 0);
        }
        __syncthreads();
    }

#pragma unroll
    for (int i = 0; i < 4; ++i) {
        const int gm = m0 + wm + i * 16 + lq * 4;
#pragma unroll
        for (int j = 0; j < 4; ++j) {
            const int gn = n0 + wn + j * 16 + lm;
            const float bv = bias ? bias[gn] : 0.f;
#pragma unroll
            for (int r = 0; r < 4; ++r)
                store_v(&C[(size_t)(gm + r) * Nn + gn], acc[i][j][r] + bv);
        }
    }
}

// ---------------------------------------------------------------------------
// Fallback vector GEMM (K=92 aw1, tiny fc head)
// ---------------------------------------------------------------------------
template <typename AT, typename CT>
__global__ __launch_bounds__(256) void gemm_bias(
    const AT* __restrict__ A, const float* __restrict__ W,
    const float* __restrict__ bias, CT* __restrict__ C,
    int M, int Nn, int K)
{
    __shared__ float As[16][65];
    __shared__ float Ws[16][65];
    const int m0 = blockIdx.x * 64;
    const int n0 = blockIdx.y * 64;
    const int tid = threadIdx.x;
    const int tx = tid & 15, ty = tid >> 4;
    float acc[4][4] = {};

    for (int k0 = 0; k0 < K; k0 += 16) {
        {
            const int ar = tid >> 2;
            const int ac = (tid & 3) * 4;
            const int gm = m0 + ar;
#pragma unroll
            for (int j = 0; j < 4; ++j) {
                const int gk = k0 + ac + j;
                float v = 0.f;
                if (gm < M && gk < K) v = to_f(A[(size_t)gm * K + gk]);
                As[ac + j][ar] = v;
            }
        }
        {
            const int wr = tid >> 4;
            const int wc = (tid & 15) * 4;
            const int gk = k0 + wr;
#pragma unroll
            for (int j = 0; j < 4; ++j) {
                float v = 0.f;
                if (gk < K) v = W[(size_t)gk * Nn + n0 + wc + j];
                Ws[wr][wc + j] = v;
            }
        }
        __syncthreads();
#pragma unroll
        for (int kk = 0; kk < 16; ++kk) {
            float a[4], b[4];
#pragma unroll
            for (int i = 0; i < 4; ++i) a[i] = As[kk][ty * 4 + i];
#pragma unroll
            for (int j = 0; j < 4; ++j) b[j] = Ws[kk][tx * 4 + j];
#pragma unroll
            for (int i = 0; i < 4; ++i)
#pragma unroll
                for (int j = 0; j < 4; ++j) acc[i][j] += a[i] * b[j];
        }
        __syncthreads();
    }
#pragma unroll
    for (int i = 0; i < 4; ++i) {
        const int gm = m0 + ty * 4 + i;
        if (gm >= M) continue;
#pragma unroll
        for (int j = 0; j < 4; ++j) {
            const int gn = n0 + tx * 4 + j;
            float v = acc[i][j];
            if (bias) v += bias[gn];
            store_v(&C[(size_t)gm * Nn + gn], v);
        }
    }
}

// ---------------------------------------------------------------------------
// RBF expansion -> bf16.  4 edges per block, 4 cols per thread, packed store.
// ---------------------------------------------------------------------------
__global__ __launch_bounds__(256) void rbf_kernel(
    const float* __restrict__ ea, bf16* __restrict__ rbf)
{
    const int e = blockIdx.x * 4 + (threadIdx.x >> 6);
    const int c0 = (threadIdx.x & 63) * 4;
    const float ax = ea[e * 3 + 0];
    const float ay = ea[e * 3 + 1];
    const float az = ea[e * 3 + 2];
    const float d = sqrtf(ax * ax + ay * ay + az * az);
    const float step = 8.0f / 255.0f;
    const float gamma = 1.0f / (step * step);
    float o[4];
#pragma unroll
    for (int j = 0; j < 4; ++j) {
        const float t = d - (float)(c0 + j) * step;
        o[j] = __expf(-gamma * t * t);
    }
    store_f4(rbf + (size_t)e * DD + c0, make_float4(o[0], o[1], o[2], o[3]));
}

// ---------------------------------------------------------------------------
// Row LayerNorm (+opt SiLU, +opt fp32 residual). 16 lanes/row, 16 elems/lane,
// xor-butterfly reduction (4 steps, serves 4 rows per wave simultaneously).
// grid = rows/16.
// ---------------------------------------------------------------------------
template <typename XT, typename YT>
__global__ __launch_bounds__(256) void ln_act_kernel(
    const XT* __restrict__ X, YT* __restrict__ Y,
    const float* __restrict__ g, const float* __restrict__ b,
    const float* __restrict__ resid, int rows, int do_silu)
{
    const int lane = threadIdx.x & 63;
    const int wave = threadIdx.x >> 6;
    const int r = blockIdx.x * 16 + wave * 4 + (lane >> 4);
    const int li = lane & 15;
    if (r >= rows) return;
    const int c0 = li * 16;
    float v[16];
    load16(X + (size_t)r * DD + c0, v);
    float s = 0.f, q = 0.f;
#pragma unroll
    for (int i = 0; i < 16; ++i) { s += v[i]; q += v[i] * v[i]; }
#pragma unroll
    for (int m = 1; m < 16; m <<= 1) {
        s += __shfl_xor(s, m);
        q += __shfl_xor(q, m);
    }
    const float mean = s * (1.f / 256.f);
    const float var = q * (1.f / 256.f) - mean * mean;
    const float rs = rsqrtf(var + 1e-5f);
#pragma unroll
    for (int i = 0; i < 16; ++i) {
        float o = (v[i] - mean) * rs * g[c0 + i] + b[c0 + i];
        if (do_silu) o = o / (1.f + __expf(-o));
        v[i] = o;
    }
    if (resid) {
#pragma unroll
        for (int i = 0; i < 4; ++i) {
            const float4 rv = load4(resid + (size_t)r * DD + c0 + i * 4);
            v[i * 4 + 0] += rv.x; v[i * 4 + 1] += rv.y;
            v[i * 4 + 2] += rv.z; v[i * 4 + 3] += rv.w;
        }
    }
    YT* yp = Y + (size_t)r * DD + c0;
#pragma unroll
    for (int i = 0; i < 4; ++i)
        store_f4(yp + i * 4,
                 make_float4(v[i * 4], v[i * 4 + 1], v[i * 4 + 2], v[i * 4 + 3]));
}

// ---------------------------------------------------------------------------
// CSR build: histogram, block-scan, fill
// ---------------------------------------------------------------------------
__global__ __launch_bounds__(256) void deg_kernel(
    const int* __restrict__ dst, int* __restrict__ deg)
{
    const int e = blockIdx.x * 256 + threadIdx.x;
    if (e < EE) atomicAdd(&deg[dst[e]], 1);
}

__global__ __launch_bounds__(256) void csr_scan(
    const int* __restrict__ deg, int* __restrict__ rowptr)
{
    __shared__ int part[256];
    const int t = threadIdx.x;
    int local[32];
    int s = 0;
#pragma unroll
    for (int i = 0; i < 32; ++i) { local[i] = deg[t * 32 + i]; s += local[i]; }
    part[t] = s;
    __syncthreads();
    if (t == 0) {
        int run = 0;
        for (int i = 0; i < 256; ++i) { const int v = part[i]; part[i] = run; run += v; }
    }
    __syncthreads();
    int run = part[t];
#pragma unroll
    for (int i = 0; i < 32; ++i) { rowptr[t * 32 + i] = run; run += local[i]; }
    if (t == 255) rowptr[NN] = run;
}

__global__ __launch_bounds__(256) void fill_kernel(
    const int* __restrict__ dst, const int* __restrict__ rowptr,
    int* __restrict__ fill, int* __restrict__ eid)
{
    const int e = blockIdx.x * 256 + threadIdx.x;
    if (e >= EE) return;
    const int d = dst[e];
    const int pos = atomicAdd(&fill[d], 1);
    eid[rowptr[d] + pos] = e;
}

// ---------------------------------------------------------------------------
// Single-pass fused attention (flash-style online softmax), no atomics.
// ---------------------------------------------------------------------------
__global__ __launch_bounds__(256) void attn_kernel(
    const bf16* __restrict__ qkv, const bf16* __restrict__ ee,
    const int* __restrict__ rowptr, const int* __restrict__ eid,
    const int* __restrict__ src, float* __restrict__ msg)
{
    const int n = blockIdx.x;
    const int tid = threadIdx.x;
    const int wave = tid >> 6, lane = tid & 63;
    const int e0 = rowptr[n];
    const int deg = rowptr[n + 1] - e0;

    if (deg == 0) {  // uniform branch
        msg[(size_t)n * DD + tid] = 0.f;
        return;
    }

    __shared__ float wm[4][HH];
    __shared__ float wl[4][HH];
    __shared__ float wacc[4][DD];

    const float4 qreg = load4(qkv + (size_t)n * 768 + lane * 4);

    float m = -3.402823466e38f, l = 0.f;
    float4 acc = {0.f, 0.f, 0.f, 0.f};

    for (int j = wave; j < deg; j += 4) {
        const int e = eid[e0 + j];
        const int s_ = src[e];
        const bf16* srow = qkv + (size_t)s_ * 768;
        const float4 kv = load4(srow + 256 + lane * 4);
        const float4 vv = load4(srow + 512 + lane * 4);
        const float4 ev = load4(ee + (size_t)e * DD + lane * 4);
        float p = qreg.x * (kv.x + ev.x) + qreg.y * (kv.y + ev.y) +
                  qreg.z * (kv.z + ev.z) + qreg.w * (kv.w + ev.w);
        p += __shfl_down(p, 4);
        p += __shfl_down(p, 2);
        p += __shfl_down(p, 1);
        const float s = __shfl(p, lane & 56) * 0.17677669529663687f;
        const float mnew = fmaxf(m, s);
        const float scale = __expf(m - mnew);
        const float pe = __expf(s - mnew);
        l = l * scale + pe;
        acc.x = acc.x * scale + pe * (vv.x + ev.x);
        acc.y = acc.y * scale + pe * (vv.y + ev.y);
        acc.z = acc.z * scale + pe * (vv.z + ev.z);
        acc.w = acc.w * scale + pe * (vv.w + ev.w);
        m = mnew;
    }

    if ((lane & 7) == 0) { wm[wave][lane >> 3] = m; wl[wave][lane >> 3] = l; }
    *(float4*)(&wacc[wave][lane * 4]) = acc;
    __syncthreads();

    {
        const int c = tid, h = tid >> 5;
        float M = wm[0][h];
#pragma unroll
        for (int i = 1; i < 4; ++i) M = fmaxf(M, wm[i][h]);
        float L = 0.f, num = 0.f;
#pragma unroll
        for (int i = 0; i < 4; ++i) {
            const float sc = __expf(wm[i][h] - M);
            L += wl[i][h] * sc;
            num += wacc[i][c] * sc;
        }
        msg[(size_t)n * DD + c] = num / (L + 1e-16f);
    }
}

__global__ __launch_bounds__(256) void zero_kernel(float* __restrict__ p, int n)
{
    const int i = blockIdx.x * 256 + threadIdx.x;
    if (i < n) p[i] = 0.f;
}

__global__ __launch_bounds__(256) void pool_kernel(
    const float* __restrict__ node, const int* __restrict__ batch,
    float* __restrict__ sums, float* __restrict__ cnt)
{
    const int n = blockIdx.x;
    const int c = threadIdx.x;
    const int b = batch[n];
    atomicAdd(&sums[b * DD + c], node[(size_t)n * DD + c]);
    if (c == 0) atomicAdd(&cnt[b], 1.0f);
}

__global__ __launch_bounds__(256) void pooled_kernel(
    const float* __restrict__ sums, const float* __restrict__ cnt,
    float* __restrict__ pooled)
{
    const int b = blockIdx.x;
    const int c = threadIdx.x;
    float cc = cnt[b];
    if (cc < 1.f) cc = 1.f;
    pooled[b * DD + c] = sums[b * DD + c] / cc;
}

__global__ __launch_bounds__(64) void final_kernel(
    const float* __restrict__ fc, const float* __restrict__ fow,
    const float* __restrict__ fob, float* __restrict__ out)
{
    const int b = blockIdx.x;
    const int lane = threadIdx.x;
    float s = 0.f;
#pragma unroll
    for (int i = lane; i < FCD; i += 64) s += fc[(size_t)b * FCD + i] * fow[i];
    for (int off = 32; off; off >>= 1) s += __shfl_down(s, off);
    if (lane == 0) out[b] = s + fob[0];
}

// ---------------------------------------------------------------------------
extern "C" void kernel_launch(void* const* d_in, const int* in_sizes, int n_in,
                              void* d_out, int out_size, void* d_ws,
                              size_t ws_size, hipStream_t stream)
{
    const float* x         = (const float*)d_in[0];
    const float* edge_attr = (const float*)d_in[1];
    const int*   eidx      = (const int*)d_in[2];
    const int*   batch     = (const int*)d_in[3];
    const float* aw1 = (const float*)d_in[4];
    const float* ab1 = (const float*)d_in[5];
    const float* ag1 = (const float*)d_in[6];
    const float* abt1 = (const float*)d_in[7];
    const float* aw2 = (const float*)d_in[8];
    const float* ab2 = (const float*)d_in[9];
    const float* rw1 = (const float*)d_in[10];
    const float* rb1 = (const float*)d_in[11];
    const float* rg1 = (const float*)d_in[12];
    const float* rbt1 = (const float*)d_in[13];
    const float* rw2 = (const float*)d_in[14];
    const float* rb2 = (const float*)d_in[15];
    const float* rg2 = (const float*)d_in[16];
    const float* rbt2 = (const float*)d_in[17];
    const float* rw3 = (const float*)d_in[18];
    const float* rb3 = (const float*)d_in[19];
    const float* Wq = (const float*)d_in[20];
    const float* bq = (const float*)d_in[21];
    const float* Wk = (const float*)d_in[22];
    const float* bk = (const float*)d_in[23];
    const float* Wv = (const float*)d_in[24];
    const float* bv = (const float*)d_in[25];
    const float* We_ = (const float*)d_in[26];
    const float* be_ = (const float*)d_in[27];
    const float* Wo = (const float*)d_in[28];
    const float* bo = (const float*)d_in[29];
    const float* lng = (const float*)d_in[30];
    const float* lnb = (const float*)d_in[31];
    const float* fw1 = (const float*)d_in[32];
    const float* fb1 = (const float*)d_in[33];
    const float* fow = (const float*)d_in[34];
    const float* fob = (const float*)d_in[35];

    const int* src = eidx;
    const int* dst = eidx + EE;

    // workspace carve-up (~170 MB)
    char* w = (char*)d_ws;
    size_t off = 0;
    auto alloc = [&](size_t bytes) -> void* {
        void* p = w + off;
        off += (bytes + 255) & ~(size_t)255;
        return p;
    };
    bf16* e_buf = (bf16*)alloc((size_t)EE * DD * 2);   // 64 MB
    bf16* t_buf = (bf16*)alloc((size_t)EE * DD * 2);   // 64 MB
    float* node = (float*)alloc((size_t)NN * DD * 4);  // 8 MB
    bf16*  qkv  = (bf16*)alloc((size_t)NN * 768 * 2);  // 12 MB
    float* msg  = (float*)alloc((size_t)NN * DD * 4);  // 8 MB
    float* outb = (float*)alloc((size_t)NN * DD * 4);  // 8 MB
    int* deg    = (int*)alloc((size_t)NN * 4);         // | contiguous zero
    int* fillc  = (int*)alloc((size_t)NN * 4);         // | region (deg+fill)
    int* rowptr = (int*)alloc((size_t)(NN + 1) * 4);
    int* eid    = (int*)alloc((size_t)EE * 4);         // 512 KB
    float* sums  = (float*)alloc((size_t)BB * DD * 4); // | contiguous with cnt
    float* cnt   = (float*)alloc((size_t)BB * 4);      // |
    float* pooled = (float*)alloc((size_t)BB * DD * 4);
    float* fc    = (float*)alloc((size_t)BB * FCD * 4);
    __bf16* Wt  = (__bf16*)alloc((size_t)34 * 65536 * 2);  // 4.25 MB
    float* qkvb = (float*)alloc((size_t)LL * 768 * 4);     // 18 KB
    (void)ws_size; (void)n_in; (void)in_sizes; (void)out_size;

    const dim3 blk(256);
    auto WT = [&](int i) -> const __bf16* { return Wt + (size_t)i * 65536; };

    // ---- one-time prep: weight transposes, bias pack, CSR ----
    hipLaunchKernelGGL(transpose_weights, dim3(16, 34), blk, 0, stream,
                       rw1, rw2, rw3, aw2, Wq, Wk, Wv, We_, Wo, Wt);
    hipLaunchKernelGGL(pack_qkv_bias, dim3((LL * 768 + 255) / 256), blk, 0, stream, bq, bk, bv, qkvb);
    hipLaunchKernelGGL(zero_kernel, dim3((2 * NN + 255) / 256), blk, 0, stream, (float*)deg, 2 * NN);
    hipLaunchKernelGGL(deg_kernel, dim3(EE / 256), blk, 0, stream, dst, deg);
    hipLaunchKernelGGL(csr_scan, dim3(1), blk, 0, stream, deg, rowptr);
    hipLaunchKernelGGL(fill_kernel, dim3(EE / 256), blk, 0, stream, dst, rowptr, fillc, eid);

    // ---- edge MLP: rbf -> L1 -> LN+SiLU -> L2 -> LN+SiLU -> L3 ----
    const dim3 geM(EE / 128, DD / 128);
    hipLaunchKernelGGL(rbf_kernel, dim3(EE / 4), blk, 0, stream, edge_attr, t_buf);
    hipLaunchKernelGGL((mfma_gemm_async<bf16>), geM, blk, 0, stream, t_buf, WT(0), rb1, e_buf, EE, DD, DD);
    hipLaunchKernelGGL((ln_act_kernel<bf16, bf16>), dim3(EE / 16), blk, 0, stream, e_buf, e_buf, rg1, rbt1, (const float*)nullptr, EE, 1);
    hipLaunchKernelGGL((mfma_gemm_async<bf16>), geM, blk, 0, stream, e_buf, WT(1), rb2, t_buf, EE, DD, DD);
    hipLaunchKernelGGL((ln_act_kernel<bf16, bf16>), dim3(EE / 16), blk, 0, stream, t_buf, t_buf, rg2, rbt2, (const float*)nullptr, EE, 1);
    hipLaunchKernelGGL((mfma_gemm_async<bf16>), geM, blk, 0, stream, t_buf, WT(2), rb3, e_buf, EE, DD, DD);

    // ---- atom embedding: x@aw1 -> LN+SiLU -> @aw2 ----
    {
        dim3 gn64(NN / 64, DD / 64);
        hipLaunchKernelGGL((gemm_bias<float, float>), gn64, blk, 0, stream, x, aw1, ab1, outb, NN, DD, F_AT);
        hipLaunchKernelGGL((ln_act_kernel<float, float>), dim3(NN / 16), blk, 0, stream, outb, outb, ag1, abt1, (const float*)nullptr, NN, 1);
        hipLaunchKernelGGL((mfma_gemm<float, float>), dim3(NN / 128, DD / 128), blk, 0, stream, outb, WT(3), ab2, node, NN, DD, DD);
    }

    // ---- L attention layers ----
    for (int l = 0; l < LL; ++l) {
        const size_t bo_ = (size_t)l * DD;
        hipLaunchKernelGGL((mfma_gemm<float, bf16>), dim3(NN / 128, 768 / 128), blk, 0, stream,
                           node, WT(4 + 5 * l), qkvb + (size_t)l * 768, qkv, NN, 768, DD);
        hipLaunchKernelGGL((mfma_gemm_async<bf16>), geM, blk, 0, stream, e_buf, WT(7 + 5 * l), be_ + bo_, t_buf, EE, DD, DD);
        hipLaunchKernelGGL(attn_kernel, dim3(NN), blk, 0, stream, qkv, t_buf, rowptr, eid, src, msg);
        hipLaunchKernelGGL((mfma_gemm<float, float>), dim3(NN / 128, DD / 128), blk, 0, stream, msg, WT(8 + 5 * l), bo + bo_, outb, NN, DD, DD);
        hipLaunchKernelGGL((ln_act_kernel<float, float>), dim3(NN / 16), blk, 0, stream, outb, node, lng + bo_, lnb + bo_, node, NN, 0);
    }

    // ---- pooling + FC head ----
    const int PZ = BB * DD + BB;
    hipLaunchKernelGGL(zero_kernel, dim3((PZ + 255) / 256), blk, 0, stream, sums, PZ);
    hipLaunchKernelGGL(pool_kernel, dim3(NN), blk, 0, stream, node, batch, sums, cnt);
    hipLaunchKernelGGL(pooled_kernel, dim3(BB), blk, 0, stream, sums, cnt, pooled);
    {
        dim3 gf(BB / 64, FCD / 64);
        hipLaunchKernelGGL((gemm_bias<float, float>), gf, blk, 0, stream, pooled, fw1, fb1, fc, BB, FCD, DD);
    }
    hipLaunchKernelGGL(final_kernel, dim3(BB), dim3(64), 0, stream, fc, fow, fob, (float*)d_out);
}

// Round 8
// 1247.014 us; speedup vs baseline: 1.1174x; 1.1174x over previous
//
#include <hip/hip_runtime.h>
#include <hip/hip_bf16.h>
#include <cstddef>

// Problem constants (Prdnet_3324304687823)
#define NN    8192
#define EE    131072
#define BB    256
#define F_AT  92
#define DD    256
#define HH    8
#define HDIM  32
#define LL    6
#define FCD   512

typedef __hip_bfloat16 bf16;
typedef __attribute__((ext_vector_type(8))) __bf16 bf16x8;
typedef __attribute__((ext_vector_type(4))) float f32x4;

__device__ __forceinline__ float to_f(float x) { return x; }
__device__ __forceinline__ float to_f(bf16 x) { return __bfloat162float(x); }
__device__ __forceinline__ float bfu(unsigned short u) {
    return __uint_as_float(((unsigned)u) << 16);
}
__device__ __forceinline__ unsigned short bfbits(float x) {
    bf16 h = __float2bfloat16(x);
    return *(unsigned short*)&h;
}
__device__ __forceinline__ void store_v(float* p, float v) { *p = v; }
__device__ __forceinline__ void store_v(bf16* p, float v) { *p = __float2bfloat16(v); }

__device__ __forceinline__ float4 load4(const float* p) { return *(const float4*)p; }
__device__ __forceinline__ float4 load4(const bf16* p) {
    const ushort4 r = *(const ushort4*)p;
    return make_float4(bfu(r.x), bfu(r.y), bfu(r.z), bfu(r.w));
}

// packed 4-element store (16 B fp32 / 8 B bf16)
__device__ __forceinline__ void store_f4(float* p, const float4& f) {
    *(float4*)p = f;
}
__device__ __forceinline__ void store_f4(bf16* p, const float4& f) {
    ushort4 u = {bfbits(f.x), bfbits(f.y), bfbits(f.z), bfbits(f.w)};
    *(ushort4*)p = u;
}

__device__ __forceinline__ bf16x8 ld8(const bf16* p) { return *(const bf16x8*)p; }
__device__ __forceinline__ bf16x8 ld8(const float* p) {
    const float4 f0 = *(const float4*)p;
    const float4 f1 = *(const float4*)(p + 4);
    bf16x8 r;
    r[0] = (__bf16)f0.x; r[1] = (__bf16)f0.y; r[2] = (__bf16)f0.z; r[3] = (__bf16)f0.w;
    r[4] = (__bf16)f1.x; r[5] = (__bf16)f1.y; r[6] = (__bf16)f1.z; r[7] = (__bf16)f1.w;
    return r;
}

// async global->LDS, 16 B per lane; LDS dest = wave-uniform base + lane*16
__device__ __forceinline__ void async_copy16(const void* g, void* l) {
    __builtin_amdgcn_global_load_lds(
        (const __attribute__((address_space(1))) unsigned int*)g,
        (__attribute__((address_space(3))) unsigned int*)l, 16, 0, 0);
}

// ---------------------------------------------------------------------------
// Batched weight transpose: out[midx][n][k] = (bf16) src[midx][k][n]
// midx: 0=rw1 1=rw2 2=rw3 3=aw2, then per layer l: 4+5l+{0:q,1:k,2:v,3:e,4:o}
// ---------------------------------------------------------------------------
__global__ __launch_bounds__(256) void transpose_weights(
    const float* __restrict__ rw1, const float* __restrict__ rw2,
    const float* __restrict__ rw3, const float* __restrict__ aw2,
    const float* __restrict__ Wq, const float* __restrict__ Wk,
    const float* __restrict__ Wv, const float* __restrict__ We,
    const float* __restrict__ Wo, __bf16* __restrict__ out)
{
    __shared__ float tile[64][65];
    const int midx = blockIdx.y;
    const float* src;
    if (midx == 0) src = rw1;
    else if (midx == 1) src = rw2;
    else if (midx == 2) src = rw3;
    else if (midx == 3) src = aw2;
    else {
        const int l = (midx - 4) / 5, s = (midx - 4) % 5;
        const float* bases[5] = {Wq, Wk, Wv, We, Wo};
        src = bases[s] + (size_t)l * 65536;
    }
    __bf16* dst = out + (size_t)midx * 65536;
    const int k0 = (blockIdx.x >> 2) * 64;
    const int n0 = (blockIdx.x & 3) * 64;
    const int c = threadIdx.x & 63;
    const int r0 = threadIdx.x >> 6;
#pragma unroll
    for (int p = 0; p < 16; ++p) {
        const int r = r0 + p * 4;
        tile[r][c] = src[(size_t)(k0 + r) * 256 + n0 + c];
    }
    __syncthreads();
#pragma unroll
    for (int p = 0; p < 16; ++p) {
        const int n = r0 + p * 4;
        dst[(size_t)(n0 + n) * 256 + k0 + c] = (__bf16)tile[c][n];
    }
}

// pack per-layer [bq|bk|bv] -> qkvb[l*768 + ...]
__global__ __launch_bounds__(256) void pack_qkv_bias(
    const float* __restrict__ bq, const float* __restrict__ bk,
    const float* __restrict__ bv, float* __restrict__ out)
{
    const int i = blockIdx.x * 256 + threadIdx.x;
    if (i >= LL * 768) return;
    const int l = i / 768, r = i % 768;
    const float* s = (r < 256) ? bq : (r < 512) ? bk : bv;
    out[i] = s[l * 256 + (r & 255)];
}

// ---------------------------------------------------------------------------
// MFMA GEMM, async staging (A bf16 only): C = A@W + bias, Wt[Nn][K] bf16.
// 128x128 tile, BK=64, 4 waves 2x2, global_load_lds width=16, unpadded LDS.
// ---------------------------------------------------------------------------
template <typename CT>
__global__ __launch_bounds__(256) void mfma_gemm_async(
    const bf16* __restrict__ A, const __bf16* __restrict__ Wt,
    const float* __restrict__ bias, CT* __restrict__ C,
    int M, int Nn, int K)
{
    __shared__ __align__(16) __bf16 As[128 * 64];
    __shared__ __align__(16) __bf16 Bs[128 * 64];
    const int tid = threadIdx.x;
    const int m0 = blockIdx.x * 128;
    const int n0 = blockIdx.y * 128;
    const int wave = tid >> 6, lane = tid & 63;
    const int wm = (wave & 1) * 64, wn = (wave >> 1) * 64;
    const int lm = lane & 15, lq = lane >> 4;
    const int lrow = lane >> 3;          // 0..7 within 8-row chunk
    const int lcol = (lane & 7) * 8;     // elem offset 0..56

    f32x4 acc[4][4] = {};

    for (int k0 = 0; k0 < K; k0 += 64) {
#pragma unroll
        for (int p = 0; p < 4; ++p) {
            const int rbase = wave * 32 + p * 8;
            async_copy16(A  + (size_t)(m0 + rbase + lrow) * K + k0 + lcol,
                         As + rbase * 64);
            async_copy16(Wt + (size_t)(n0 + rbase + lrow) * K + k0 + lcol,
                         Bs + rbase * 64);
        }
        __syncthreads();  // drains vmcnt (global_load_lds) + barrier
#pragma unroll
        for (int ks = 0; ks < 2; ++ks) {
            bf16x8 a[4], b[4];
#pragma unroll
            for (int i = 0; i < 4; ++i) {
                a[i] = *(const bf16x8*)(As + (wm + i * 16 + lm) * 64 + ks * 32 + lq * 8);
                b[i] = *(const bf16x8*)(Bs + (wn + i * 16 + lm) * 64 + ks * 32 + lq * 8);
            }
#pragma unroll
            for (int i = 0; i < 4; ++i)
#pragma unroll
                for (int j = 0; j < 4; ++j)
                    acc[i][j] = __builtin_amdgcn_mfma_f32_16x16x32_bf16(
                        a[i], b[j], acc[i][j], 0, 0, 0);
        }
        __syncthreads();
    }

    // C/D: col = lane&15, row = (lane>>4)*4 + reg
#pragma unroll
    for (int i = 0; i < 4; ++i) {
        const int gm = m0 + wm + i * 16 + lq * 4;
#pragma unroll
        for (int j = 0; j < 4; ++j) {
            const int gn = n0 + wn + j * 16 + lm;
            const float bv = bias ? bias[gn] : 0.f;
#pragma unroll
            for (int r = 0; r < 4; ++r)
                store_v(&C[(size_t)(gm + r) * Nn + gn], acc[i][j][r] + bv);
        }
    }
}

// ---------------------------------------------------------------------------
// MFMA GEMM, register staging (fp32 A): padded LDS, conflict-free.
// ---------------------------------------------------------------------------
template <typename AT, typename CT>
__global__ __launch_bounds__(256) void mfma_gemm(
    const AT* __restrict__ A, const __bf16* __restrict__ Wt,
    const float* __restrict__ bias, CT* __restrict__ C,
    int M, int Nn, int K)
{
    __shared__ __align__(16) __bf16 As[128 * 72];
    __shared__ __align__(16) __bf16 Bs[128 * 72];
    const int tid = threadIdx.x;
    const int m0 = blockIdx.x * 128;
    const int n0 = blockIdx.y * 128;
    const int wave = tid >> 6, lane = tid & 63;
    const int wm = (wave & 1) * 64, wn = (wave >> 1) * 64;
    const int lm = lane & 15, lq = lane >> 4;

    f32x4 acc[4][4] = {};

    const int srow = tid >> 3;
    const int scol = (tid & 7) * 8;

    for (int k0 = 0; k0 < K; k0 += 64) {
#pragma unroll
        for (int p = 0; p < 4; ++p) {
            const int r = srow + 32 * p;
            *(bf16x8*)(As + r * 72 + scol) = ld8(A + (size_t)(m0 + r) * K + k0 + scol);
            *(bf16x8*)(Bs + r * 72 + scol) = *(const bf16x8*)(Wt + (size_t)(n0 + r) * K + k0 + scol);
        }
        __syncthreads();
#pragma unroll
        for (int ks = 0; ks < 2; ++ks) {
            bf16x8 a[4], b[4];
#pragma unroll
            for (int i = 0; i < 4; ++i) {
                a[i] = *(const bf16x8*)(As + (wm + i * 16 + lm) * 72 + ks * 32 + lq * 8);
                b[i] = *(const bf16x8*)(Bs + (wn + i * 16 + lm) * 72 + ks * 32 + lq * 8);
            }
#pragma unroll
            for (int i = 0; i < 4; ++i)
#pragma unroll
                for (int j = 0; j < 4; ++j)
                    acc[i][j] = __builtin_amdgcn_mfma_f32_16x16x32_bf16(
                        a[i], b[j], acc[i][j], 0, 0, 0);
        }
        __syncthreads();
    }

#pragma unroll
    for (int i = 0; i < 4; ++i) {
        const int gm = m0 + wm + i * 16 + lq * 4;
#pragma unroll
        for (int j = 0; j < 4; ++j) {
            const int gn = n0 + wn + j * 16 + lm;
            const float bv = bias ? bias[gn] : 0.f;
#pragma unroll
            for (int r = 0; r < 4; ++r)
                store_v(&C[(size_t)(gm + r) * Nn + gn], acc[i][j][r] + bv);
        }
    }
}

// ---------------------------------------------------------------------------
// Fallback vector GEMM (K=92 aw1, tiny fc head)
// ---------------------------------------------------------------------------
template <typename AT, typename CT>
__global__ __launch_bounds__(256) void gemm_bias(
    const AT* __restrict__ A, const float* __restrict__ W,
    const float* __restrict__ bias, CT* __restrict__ C,
    int M, int Nn, int K)
{
    __shared__ float As[16][65];
    __shared__ float Ws[16][65];
    const int m0 = blockIdx.x * 64;
    const int n0 = blockIdx.y * 64;
    const int tid = threadIdx.x;
    const int tx = tid & 15, ty = tid >> 4;
    float acc[4][4] = {};

    for (int k0 = 0; k0 < K; k0 += 16) {
        {
            const int ar = tid >> 2;
            const int ac = (tid & 3) * 4;
            const int gm = m0 + ar;
#pragma unroll
            for (int j = 0; j < 4; ++j) {
                const int gk = k0 + ac + j;
                float v = 0.f;
                if (gm < M && gk < K) v = to_f(A[(size_t)gm * K + gk]);
                As[ac + j][ar] = v;
            }
        }
        {
            const int wr = tid >> 4;
            const int wc = (tid & 15) * 4;
            const int gk = k0 + wr;
#pragma unroll
            for (int j = 0; j < 4; ++j) {
                float v = 0.f;
                if (gk < K) v = W[(size_t)gk * Nn + n0 + wc + j];
                Ws[wr][wc + j] = v;
            }
        }
        __syncthreads();
#pragma unroll
        for (int kk = 0; kk < 16; ++kk) {
            float a[4], b[4];
#pragma unroll
            for (int i = 0; i < 4; ++i) a[i] = As[kk][ty * 4 + i];
#pragma unroll
            for (int j = 0; j < 4; ++j) b[j] = Ws[kk][tx * 4 + j];
#pragma unroll
            for (int i = 0; i < 4; ++i)
#pragma unroll
                for (int j = 0; j < 4; ++j) acc[i][j] += a[i] * b[j];
        }
        __syncthreads();
    }
#pragma unroll
    for (int i = 0; i < 4; ++i) {
        const int gm = m0 + ty * 4 + i;
        if (gm >= M) continue;
#pragma unroll
        for (int j = 0; j < 4; ++j) {
            const int gn = n0 + tx * 4 + j;
            float v = acc[i][j];
            if (bias) v += bias[gn];
            store_v(&C[(size_t)gm * Nn + gn], v);
        }
    }
}

// ---------------------------------------------------------------------------
// RBF expansion -> bf16.  4 edges per block, 4 cols per thread, packed store.
// ---------------------------------------------------------------------------
__global__ __launch_bounds__(256) void rbf_kernel(
    const float* __restrict__ ea, bf16* __restrict__ rbf)
{
    const int e = blockIdx.x * 4 + (threadIdx.x >> 6);
    const int c0 = (threadIdx.x & 63) * 4;
    const float ax = ea[e * 3 + 0];
    const float ay = ea[e * 3 + 1];
    const float az = ea[e * 3 + 2];
    const float d = sqrtf(ax * ax + ay * ay + az * az);
    const float step = 8.0f / 255.0f;
    const float gamma = 1.0f / (step * step);
    float o[4];
#pragma unroll
    for (int j = 0; j < 4; ++j) {
        const float t = d - (float)(c0 + j) * step;
        o[j] = __expf(-gamma * t * t);
    }
    store_f4(rbf + (size_t)e * DD + c0, make_float4(o[0], o[1], o[2], o[3]));
}

// ---------------------------------------------------------------------------
// Row LayerNorm (+opt SiLU via __expf, +opt fp32 residual).
// R6 structure: 1 row per 64-lane wave (fully-coalesced 8B/lane bf16 loads),
// 4 rows per 256-thread block. R7's 16-lane variant broke coalescing — reverted.
// ---------------------------------------------------------------------------
template <typename XT, typename YT>
__global__ __launch_bounds__(256) void ln_act_kernel(
    const XT* __restrict__ X, YT* __restrict__ Y,
    const float* __restrict__ g, const float* __restrict__ b,
    const float* __restrict__ resid, int rows, int do_silu)
{
    const int wave = threadIdx.x >> 6;
    const int lane = threadIdx.x & 63;
    const int r = blockIdx.x * 4 + wave;
    if (r >= rows) return;
    const float4 x = load4(X + (size_t)r * DD + lane * 4);
    float s = x.x + x.y + x.z + x.w;
    float q = x.x * x.x + x.y * x.y + x.z * x.z + x.w * x.w;
    for (int off = 32; off; off >>= 1) {
        s += __shfl_down(s, off);
        q += __shfl_down(q, off);
    }
    s = __shfl(s, 0);
    q = __shfl(q, 0);
    const float mean = s * (1.f / 256.f);
    const float var = q * (1.f / 256.f) - mean * mean;
    const float rs = rsqrtf(var + 1e-5f);
    const int c = lane * 4;
    float xs[4] = {x.x, x.y, x.z, x.w};
    float out[4];
#pragma unroll
    for (int i = 0; i < 4; ++i) {
        float v = (xs[i] - mean) * rs * g[c + i] + b[c + i];
        if (do_silu) v = v / (1.f + __expf(-v));
        out[i] = v;
    }
    if (resid) {
        const float4 rv = load4(resid + (size_t)r * DD + c);
        out[0] += rv.x; out[1] += rv.y; out[2] += rv.z; out[3] += rv.w;
    }
    store_f4(Y + (size_t)r * DD + c, make_float4(out[0], out[1], out[2], out[3]));
}

// ---------------------------------------------------------------------------
// CSR build: histogram, block-scan, fill
// ---------------------------------------------------------------------------
__global__ __launch_bounds__(256) void deg_kernel(
    const int* __restrict__ dst, int* __restrict__ deg)
{
    const int e = blockIdx.x * 256 + threadIdx.x;
    if (e < EE) atomicAdd(&deg[dst[e]], 1);
}

__global__ __launch_bounds__(256) void csr_scan(
    const int* __restrict__ deg, int* __restrict__ rowptr)
{
    __shared__ int part[256];
    const int t = threadIdx.x;
    int local[32];
    int s = 0;
#pragma unroll
    for (int i = 0; i < 32; ++i) { local[i] = deg[t * 32 + i]; s += local[i]; }
    part[t] = s;
    __syncthreads();
    if (t == 0) {
        int run = 0;
        for (int i = 0; i < 256; ++i) { const int v = part[i]; part[i] = run; run += v; }
    }
    __syncthreads();
    int run = part[t];
#pragma unroll
    for (int i = 0; i < 32; ++i) { rowptr[t * 32 + i] = run; run += local[i]; }
    if (t == 255) rowptr[NN] = run;
}

__global__ __launch_bounds__(256) void fill_kernel(
    const int* __restrict__ dst, const int* __restrict__ rowptr,
    int* __restrict__ fill, int* __restrict__ eid)
{
    const int e = blockIdx.x * 256 + threadIdx.x;
    if (e >= EE) return;
    const int d = dst[e];
    const int pos = atomicAdd(&fill[d], 1);
    eid[rowptr[d] + pos] = e;
}

// ---------------------------------------------------------------------------
// Single-pass fused attention (flash-style online softmax), no atomics.
// ---------------------------------------------------------------------------
__global__ __launch_bounds__(256) void attn_kernel(
    const bf16* __restrict__ qkv, const bf16* __restrict__ ee,
    const int* __restrict__ rowptr, const int* __restrict__ eid,
    const int* __restrict__ src, float* __restrict__ msg)
{
    const int n = blockIdx.x;
    const int tid = threadIdx.x;
    const int wave = tid >> 6, lane = tid & 63;
    const int e0 = rowptr[n];
    const int deg = rowptr[n + 1] - e0;

    if (deg == 0) {  // uniform branch
        msg[(size_t)n * DD + tid] = 0.f;
        return;
    }

    __shared__ float wm[4][HH];
    __shared__ float wl[4][HH];
    __shared__ float wacc[4][DD];

    const float4 qreg = load4(qkv + (size_t)n * 768 + lane * 4);

    float m = -3.402823466e38f, l = 0.f;
    float4 acc = {0.f, 0.f, 0.f, 0.f};

    for (int j = wave; j < deg; j += 4) {
        const int e = eid[e0 + j];
        const int s_ = src[e];
        const bf16* srow = qkv + (size_t)s_ * 768;
        const float4 kv = load4(srow + 256 + lane * 4);
        const float4 vv = load4(srow + 512 + lane * 4);
        const float4 ev = load4(ee + (size_t)e * DD + lane * 4);
        float p = qreg.x * (kv.x + ev.x) + qreg.y * (kv.y + ev.y) +
                  qreg.z * (kv.z + ev.z) + qreg.w * (kv.w + ev.w);
        p += __shfl_down(p, 4);
        p += __shfl_down(p, 2);
        p += __shfl_down(p, 1);
        const float s = __shfl(p, lane & 56) * 0.17677669529663687f;
        const float mnew = fmaxf(m, s);
        const float scale = __expf(m - mnew);
        const float pe = __expf(s - mnew);
        l = l * scale + pe;
        acc.x = acc.x * scale + pe * (vv.x + ev.x);
        acc.y = acc.y * scale + pe * (vv.y + ev.y);
        acc.z = acc.z * scale + pe * (vv.z + ev.z);
        acc.w = acc.w * scale + pe * (vv.w + ev.w);
        m = mnew;
    }

    if ((lane & 7) == 0) { wm[wave][lane >> 3] = m; wl[wave][lane >> 3] = l; }
    *(float4*)(&wacc[wave][lane * 4]) = acc;
    __syncthreads();

    {
        const int c = tid, h = tid >> 5;
        float M = wm[0][h];
#pragma unroll
        for (int i = 1; i < 4; ++i) M = fmaxf(M, wm[i][h]);
        float L = 0.f, num = 0.f;
#pragma unroll
        for (int i = 0; i < 4; ++i) {
            const float sc = __expf(wm[i][h] - M);
            L += wl[i][h] * sc;
            num += wacc[i][c] * sc;
        }
        msg[(size_t)n * DD + c] = num / (L + 1e-16f);
    }
}

__global__ __launch_bounds__(256) void zero_kernel(float* __restrict__ p, int n)
{
    const int i = blockIdx.x * 256 + threadIdx.x;
    if (i < n) p[i] = 0.f;
}

__global__ __launch_bounds__(256) void pool_kernel(
    const float* __restrict__ node, const int* __restrict__ batch,
    float* __restrict__ sums, float* __restrict__ cnt)
{
    const int n = blockIdx.x;
    const int c = threadIdx.x;
    const int b = batch[n];
    atomicAdd(&sums[b * DD + c], node[(size_t)n * DD + c]);
    if (c == 0) atomicAdd(&cnt[b], 1.0f);
}

__global__ __launch_bounds__(256) void pooled_kernel(
    const float* __restrict__ sums, const float* __restrict__ cnt,
    float* __restrict__ pooled)
{
    const int b = blockIdx.x;
    const int c = threadIdx.x;
    float cc = cnt[b];
    if (cc < 1.f) cc = 1.f;
    pooled[b * DD + c] = sums[b * DD + c] / cc;
}

__global__ __launch_bounds__(64) void final_kernel(
    const float* __restrict__ fc, const float* __restrict__ fow,
    const float* __restrict__ fob, float* __restrict__ out)
{
    const int b = blockIdx.x;
    const int lane = threadIdx.x;
    float s = 0.f;
#pragma unroll
    for (int i = lane; i < FCD; i += 64) s += fc[(size_t)b * FCD + i] * fow[i];
    for (int off = 32; off; off >>= 1) s += __shfl_down(s, off);
    if (lane == 0) out[b] = s + fob[0];
}

// ---------------------------------------------------------------------------
extern "C" void kernel_launch(void* const* d_in, const int* in_sizes, int n_in,
                              void* d_out, int out_size, void* d_ws,
                              size_t ws_size, hipStream_t stream)
{
    const float* x         = (const float*)d_in[0];
    const float* edge_attr = (const float*)d_in[1];
    const int*   eidx      = (const int*)d_in[2];
    const int*   batch     = (const int*)d_in[3];
    const float* aw1 = (const float*)d_in[4];
    const float* ab1 = (const float*)d_in[5];
    const float* ag1 = (const float*)d_in[6];
    const float* abt1 = (const float*)d_in[7];
    const float* aw2 = (const float*)d_in[8];
    const float* ab2 = (const float*)d_in[9];
    const float* rw1 = (const float*)d_in[10];
    const float* rb1 = (const float*)d_in[11];
    const float* rg1 = (const float*)d_in[12];
    const float* rbt1 = (const float*)d_in[13];
    const float* rw2 = (const float*)d_in[14];
    const float* rb2 = (const float*)d_in[15];
    const float* rg2 = (const float*)d_in[16];
    const float* rbt2 = (const float*)d_in[17];
    const float* rw3 = (const float*)d_in[18];
    const float* rb3 = (const float*)d_in[19];
    const float* Wq = (const float*)d_in[20];
    const float* bq = (const float*)d_in[21];
    const float* Wk = (const float*)d_in[22];
    const float* bk = (const float*)d_in[23];
    const float* Wv = (const float*)d_in[24];
    const float* bv = (const float*)d_in[25];
    const float* We_ = (const float*)d_in[26];
    const float* be_ = (const float*)d_in[27];
    const float* Wo = (const float*)d_in[28];
    const float* bo = (const float*)d_in[29];
    const float* lng = (const float*)d_in[30];
    const float* lnb = (const float*)d_in[31];
    const float* fw1 = (const float*)d_in[32];
    const float* fb1 = (const float*)d_in[33];
    const float* fow = (const float*)d_in[34];
    const float* fob = (const float*)d_in[35];

    const int* src = eidx;
    const int* dst = eidx + EE;

    // workspace carve-up (~170 MB)
    char* w = (char*)d_ws;
    size_t off = 0;
    auto alloc = [&](size_t bytes) -> void* {
        void* p = w + off;
        off += (bytes + 255) & ~(size_t)255;
        return p;
    };
    bf16* e_buf = (bf16*)alloc((size_t)EE * DD * 2);   // 64 MB
    bf16* t_buf = (bf16*)alloc((size_t)EE * DD * 2);   // 64 MB
    float* node = (float*)alloc((size_t)NN * DD * 4);  // 8 MB
    bf16*  qkv  = (bf16*)alloc((size_t)NN * 768 * 2);  // 12 MB
    float* msg  = (float*)alloc((size_t)NN * DD * 4);  // 8 MB
    float* outb = (float*)alloc((size_t)NN * DD * 4);  // 8 MB
    int* deg    = (int*)alloc((size_t)NN * 4);         // | contiguous zero
    int* fillc  = (int*)alloc((size_t)NN * 4);         // | region (deg+fill)
    int* rowptr = (int*)alloc((size_t)(NN + 1) * 4);
    int* eid    = (int*)alloc((size_t)EE * 4);         // 512 KB
    float* sums  = (float*)alloc((size_t)BB * DD * 4); // | contiguous with cnt
    float* cnt   = (float*)alloc((size_t)BB * 4);      // |
    float* pooled = (float*)alloc((size_t)BB * DD * 4);
    float* fc    = (float*)alloc((size_t)BB * FCD * 4);
    __bf16* Wt  = (__bf16*)alloc((size_t)34 * 65536 * 2);  // 4.25 MB
    float* qkvb = (float*)alloc((size_t)LL * 768 * 4);     // 18 KB
    (void)ws_size; (void)n_in; (void)in_sizes; (void)out_size;

    const dim3 blk(256);
    auto WT = [&](int i) -> const __bf16* { return Wt + (size_t)i * 65536; };

    // ---- one-time prep: weight transposes, bias pack, CSR ----
    hipLaunchKernelGGL(transpose_weights, dim3(16, 34), blk, 0, stream,
                       rw1, rw2, rw3, aw2, Wq, Wk, Wv, We_, Wo, Wt);
    hipLaunchKernelGGL(pack_qkv_bias, dim3((LL * 768 + 255) / 256), blk, 0, stream, bq, bk, bv, qkvb);
    hipLaunchKernelGGL(zero_kernel, dim3((2 * NN + 255) / 256), blk, 0, stream, (float*)deg, 2 * NN);
    hipLaunchKernelGGL(deg_kernel, dim3(EE / 256), blk, 0, stream, dst, deg);
    hipLaunchKernelGGL(csr_scan, dim3(1), blk, 0, stream, deg, rowptr);
    hipLaunchKernelGGL(fill_kernel, dim3(EE / 256), blk, 0, stream, dst, rowptr, fillc, eid);

    // ---- edge MLP: rbf -> L1 -> LN+SiLU -> L2 -> LN+SiLU -> L3 ----
    const dim3 geM(EE / 128, DD / 128);
    hipLaunchKernelGGL(rbf_kernel, dim3(EE / 4), blk, 0, stream, edge_attr, t_buf);
    hipLaunchKernelGGL((mfma_gemm_async<bf16>), geM, blk, 0, stream, t_buf, WT(0), rb1, e_buf, EE, DD, DD);
    hipLaunchKernelGGL((ln_act_kernel<bf16, bf16>), dim3(EE / 4), blk, 0, stream, e_buf, e_buf, rg1, rbt1, (const float*)nullptr, EE, 1);
    hipLaunchKernelGGL((mfma_gemm_async<bf16>), geM, blk, 0, stream, e_buf, WT(1), rb2, t_buf, EE, DD, DD);
    hipLaunchKernelGGL((ln_act_kernel<bf16, bf16>), dim3(EE / 4), blk, 0, stream, t_buf, t_buf, rg2, rbt2, (const float*)nullptr, EE, 1);
    hipLaunchKernelGGL((mfma_gemm_async<bf16>), geM, blk, 0, stream, t_buf, WT(2), rb3, e_buf, EE, DD, DD);

    // ---- atom embedding: x@aw1 -> LN+SiLU -> @aw2 ----
    {
        dim3 gn64(NN / 64, DD / 64);
        hipLaunchKernelGGL((gemm_bias<float, float>), gn64, blk, 0, stream, x, aw1, ab1, outb, NN, DD, F_AT);
        hipLaunchKernelGGL((ln_act_kernel<float, float>), dim3(NN / 4), blk, 0, stream, outb, outb, ag1, abt1, (const float*)nullptr, NN, 1);
        hipLaunchKernelGGL((mfma_gemm<float, float>), dim3(NN / 128, DD / 128), blk, 0, stream, outb, WT(3), ab2, node, NN, DD, DD);
    }

    // ---- L attention layers ----
    for (int l = 0; l < LL; ++l) {
        const size_t bo_ = (size_t)l * DD;
        hipLaunchKernelGGL((mfma_gemm<float, bf16>), dim3(NN / 128, 768 / 128), blk, 0, stream,
                           node, WT(4 + 5 * l), qkvb + (size_t)l * 768, qkv, NN, 768, DD);
        hipLaunchKernelGGL((mfma_gemm_async<bf16>), geM, blk, 0, stream, e_buf, WT(7 + 5 * l), be_ + bo_, t_buf, EE, DD, DD);
        hipLaunchKernelGGL(attn_kernel, dim3(NN), blk, 0, stream, qkv, t_buf, rowptr, eid, src, msg);
        hipLaunchKernelGGL((mfma_gemm<float, float>), dim3(NN / 128, DD / 128), blk, 0, stream, msg, WT(8 + 5 * l), bo + bo_, outb, NN, DD, DD);
        hipLaunchKernelGGL((ln_act_kernel<float, float>), dim3(NN / 4), blk, 0, stream, outb, node, lng + bo_, lnb + bo_, node, NN, 0);
    }

    // ---- pooling + FC head ----
    const int PZ = BB * DD + BB;
    hipLaunchKernelGGL(zero_kernel, dim3((PZ + 255) / 256), blk, 0, stream, sums, PZ);
    hipLaunchKernelGGL(pool_kernel, dim3(NN), blk, 0, stream, node, batch, sums, cnt);
    hipLaunchKernelGGL(pooled_kernel, dim3(BB), blk, 0, stream, sums, cnt, pooled);
    {
        dim3 gf(BB / 64, FCD / 64);
        hipLaunchKernelGGL((gemm_bias<float, float>), gf, blk, 0, stream, pooled, fw1, fb1, fc, BB, FCD, DD);
    }
    hipLaunchKernelGGL(final_kernel, dim3(BB), dim3(64), 0, stream, fc, fow, fob, (float*)d_out);
}

// Round 9
// 1173.540 us; speedup vs baseline: 1.1873x; 1.0626x over previous
//
#include <hip/hip_runtime.h>
#include <hip/hip_bf16.h>
#include <cstddef>

// Problem constants (Prdnet_3324304687823)
#define NN    8192
#define EE    131072
#define BB    256
#define F_AT  92
#define DD    256
#define HH    8
#define HDIM  32
#define LL    6
#define FCD   512

typedef __hip_bfloat16 bf16;
typedef __attribute__((ext_vector_type(8))) __bf16 bf16x8;
typedef __attribute__((ext_vector_type(4))) float f32x4;

__device__ __forceinline__ float to_f(float x) { return x; }
__device__ __forceinline__ float to_f(bf16 x) { return __bfloat162float(x); }
__device__ __forceinline__ float bfu(unsigned short u) {
    return __uint_as_float(((unsigned)u) << 16);
}
__device__ __forceinline__ unsigned short bfbits(float x) {
    bf16 h = __float2bfloat16(x);
    return *(unsigned short*)&h;
}
__device__ __forceinline__ void store_v(float* p, float v) { *p = v; }
__device__ __forceinline__ void store_v(bf16* p, float v) { *p = __float2bfloat16(v); }

__device__ __forceinline__ float4 load4(const float* p) { return *(const float4*)p; }
__device__ __forceinline__ float4 load4(const bf16* p) {
    const ushort4 r = *(const ushort4*)p;
    return make_float4(bfu(r.x), bfu(r.y), bfu(r.z), bfu(r.w));
}

// packed 4-element store (16 B fp32 / 8 B bf16)
__device__ __forceinline__ void store_f4(float* p, const float4& f) {
    *(float4*)p = f;
}
__device__ __forceinline__ void store_f4(bf16* p, const float4& f) {
    ushort4 u = {bfbits(f.x), bfbits(f.y), bfbits(f.z), bfbits(f.w)};
    *(ushort4*)p = u;
}

__device__ __forceinline__ bf16x8 ld8(const bf16* p) { return *(const bf16x8*)p; }
__device__ __forceinline__ bf16x8 ld8(const float* p) {
    const float4 f0 = *(const float4*)p;
    const float4 f1 = *(const float4*)(p + 4);
    bf16x8 r;
    r[0] = (__bf16)f0.x; r[1] = (__bf16)f0.y; r[2] = (__bf16)f0.z; r[3] = (__bf16)f0.w;
    r[4] = (__bf16)f1.x; r[5] = (__bf16)f1.y; r[6] = (__bf16)f1.z; r[7] = (__bf16)f1.w;
    return r;
}

// async global->LDS, 16 B per lane; LDS dest = wave-uniform base + lane*16
__device__ __forceinline__ void async_copy16(const void* g, void* l) {
    __builtin_amdgcn_global_load_lds(
        (const __attribute__((address_space(1))) unsigned int*)g,
        (__attribute__((address_space(3))) unsigned int*)l, 16, 0, 0);
}

// ---------------------------------------------------------------------------
// Batched weight transpose: out[midx][n][k] = (bf16) src[midx][k][n]
// midx: 0=rw1 1=rw2 2=rw3 3=aw2, then per layer l: 4+5l+{0:q,1:k,2:v,3:e,4:o}
// ---------------------------------------------------------------------------
__global__ __launch_bounds__(256) void transpose_weights(
    const float* __restrict__ rw1, const float* __restrict__ rw2,
    const float* __restrict__ rw3, const float* __restrict__ aw2,
    const float* __restrict__ Wq, const float* __restrict__ Wk,
    const float* __restrict__ Wv, const float* __restrict__ We,
    const float* __restrict__ Wo, __bf16* __restrict__ out)
{
    __shared__ float tile[64][65];
    const int midx = blockIdx.y;
    const float* src;
    if (midx == 0) src = rw1;
    else if (midx == 1) src = rw2;
    else if (midx == 2) src = rw3;
    else if (midx == 3) src = aw2;
    else {
        const int l = (midx - 4) / 5, s = (midx - 4) % 5;
        const float* bases[5] = {Wq, Wk, Wv, We, Wo};
        src = bases[s] + (size_t)l * 65536;
    }
    __bf16* dst = out + (size_t)midx * 65536;
    const int k0 = (blockIdx.x >> 2) * 64;
    const int n0 = (blockIdx.x & 3) * 64;
    const int c = threadIdx.x & 63;
    const int r0 = threadIdx.x >> 6;
#pragma unroll
    for (int p = 0; p < 16; ++p) {
        const int r = r0 + p * 4;
        tile[r][c] = src[(size_t)(k0 + r) * 256 + n0 + c];
    }
    __syncthreads();
#pragma unroll
    for (int p = 0; p < 16; ++p) {
        const int n = r0 + p * 4;
        dst[(size_t)(n0 + n) * 256 + k0 + c] = (__bf16)tile[c][n];
    }
}

// pack per-layer [bq|bk|bv] -> qkvb[l*768 + ...]
__global__ __launch_bounds__(256) void pack_qkv_bias(
    const float* __restrict__ bq, const float* __restrict__ bk,
    const float* __restrict__ bv, float* __restrict__ out)
{
    const int i = blockIdx.x * 256 + threadIdx.x;
    if (i >= LL * 768) return;
    const int l = i / 768, r = i % 768;
    const float* s = (r < 256) ? bq : (r < 512) ? bk : bv;
    out[i] = s[l * 256 + (r & 255)];
}

// ---------------------------------------------------------------------------
// Fused MFMA GEMM + LayerNorm(+SiLU): C = act(LN(A@W + bias)) for Nn=K=256.
// 128x256 tile (full row per block), 4 waves 2x2 (64 rows x 128 cols each),
// acc 4x8 frags. Row stats from fp32 acc: in-reg j-sum -> 16-lane shfl_xor
// -> 2-half LDS combine. A bf16, async staging. Output bf16.
// ---------------------------------------------------------------------------
__global__ __launch_bounds__(256) void mfma_gemm_ln(
    const bf16* __restrict__ A, const __bf16* __restrict__ Wt,
    const float* __restrict__ bias, const float* __restrict__ g,
    const float* __restrict__ b, bf16* __restrict__ C, int M, int do_silu)
{
    __shared__ __align__(16) __bf16 As[128 * 64];
    __shared__ __align__(16) __bf16 Bs[256 * 64];
    __shared__ float rsum[128][2];
    __shared__ float rsq[128][2];
    const int tid = threadIdx.x;
    const int m0 = blockIdx.x * 128;
    const int wave = tid >> 6, lane = tid & 63;
    const int wm = (wave & 1) * 64;
    const int wn = (wave >> 1) * 128;
    const int half = wave >> 1;
    const int lm = lane & 15, lq = lane >> 4;
    const int lrow = lane >> 3, lcol = (lane & 7) * 8;

    f32x4 acc[4][8] = {};

    for (int k0 = 0; k0 < 256; k0 += 64) {
#pragma unroll
        for (int p = 0; p < 4; ++p) {
            const int rbase = wave * 32 + p * 8;
            async_copy16(A + (size_t)(m0 + rbase + lrow) * 256 + k0 + lcol,
                         As + rbase * 64);
        }
#pragma unroll
        for (int p = 0; p < 8; ++p) {
            const int rbase = wave * 64 + p * 8;
            async_copy16(Wt + (size_t)(rbase + lrow) * 256 + k0 + lcol,
                         Bs + rbase * 64);
        }
        __syncthreads();
#pragma unroll
        for (int ks = 0; ks < 2; ++ks) {
            bf16x8 a[4], bf[8];
#pragma unroll
            for (int i = 0; i < 4; ++i)
                a[i] = *(const bf16x8*)(As + (wm + i * 16 + lm) * 64 + ks * 32 + lq * 8);
#pragma unroll
            for (int j = 0; j < 8; ++j)
                bf[j] = *(const bf16x8*)(Bs + (wn + j * 16 + lm) * 64 + ks * 32 + lq * 8);
#pragma unroll
            for (int i = 0; i < 4; ++i)
#pragma unroll
                for (int j = 0; j < 8; ++j)
                    acc[i][j] = __builtin_amdgcn_mfma_f32_16x16x32_bf16(
                        a[i], bf[j], acc[i][j], 0, 0, 0);
        }
        __syncthreads();
    }

    // bias add, then per-row partial sums over this wave's 128 cols
#pragma unroll
    for (int j = 0; j < 8; ++j) {
        const float bv = bias[wn + j * 16 + lm];
#pragma unroll
        for (int i = 0; i < 4; ++i)
#pragma unroll
            for (int r = 0; r < 4; ++r)
                acc[i][j][r] += bv;
    }
#pragma unroll
    for (int i = 0; i < 4; ++i) {
#pragma unroll
        for (int r = 0; r < 4; ++r) {
            float s = 0.f, q = 0.f;
#pragma unroll
            for (int j = 0; j < 8; ++j) {
                const float v = acc[i][j][r];
                s += v; q += v * v;
            }
#pragma unroll
            for (int msk = 1; msk < 16; msk <<= 1) {
                s += __shfl_xor(s, msk);
                q += __shfl_xor(q, msk);
            }
            if (lm == 0) {
                const int row = wm + i * 16 + lq * 4 + r;
                rsum[row][half] = s;
                rsq[row][half] = q;
            }
        }
    }
    __syncthreads();

    // normalize + (SiLU) + store
    float gg[8], bb[8];
#pragma unroll
    for (int j = 0; j < 8; ++j) {
        gg[j] = g[wn + j * 16 + lm];
        bb[j] = b[wn + j * 16 + lm];
    }
#pragma unroll
    for (int i = 0; i < 4; ++i) {
#pragma unroll
        for (int r = 0; r < 4; ++r) {
            const int row = wm + i * 16 + lq * 4 + r;
            const float s = rsum[row][0] + rsum[row][1];
            const float q = rsq[row][0] + rsq[row][1];
            const float mean = s * (1.f / 256.f);
            const float var = q * (1.f / 256.f) - mean * mean;
            const float rs = rsqrtf(var + 1e-5f);
            bf16* crow = C + (size_t)(m0 + row) * 256;
#pragma unroll
            for (int j = 0; j < 8; ++j) {
                float v = (acc[i][j][r] - mean) * rs * gg[j] + bb[j];
                if (do_silu) v = v / (1.f + __expf(-v));
                crow[wn + j * 16 + lm] = __float2bfloat16(v);
            }
        }
    }
}

// ---------------------------------------------------------------------------
// MFMA GEMM, async staging (A bf16 only): C = A@W + bias, Wt[Nn][K] bf16.
// 128x128 tile, BK=64, 4 waves 2x2, global_load_lds width=16, unpadded LDS.
// ---------------------------------------------------------------------------
template <typename CT>
__global__ __launch_bounds__(256) void mfma_gemm_async(
    const bf16* __restrict__ A, const __bf16* __restrict__ Wt,
    const float* __restrict__ bias, CT* __restrict__ C,
    int M, int Nn, int K)
{
    __shared__ __align__(16) __bf16 As[128 * 64];
    __shared__ __align__(16) __bf16 Bs[128 * 64];
    const int tid = threadIdx.x;
    const int m0 = blockIdx.x * 128;
    const int n0 = blockIdx.y * 128;
    const int wave = tid >> 6, lane = tid & 63;
    const int wm = (wave & 1) * 64, wn = (wave >> 1) * 64;
    const int lm = lane & 15, lq = lane >> 4;
    const int lrow = lane >> 3;          // 0..7 within 8-row chunk
    const int lcol = (lane & 7) * 8;     // elem offset 0..56

    f32x4 acc[4][4] = {};

    for (int k0 = 0; k0 < K; k0 += 64) {
#pragma unroll
        for (int p = 0; p < 4; ++p) {
            const int rbase = wave * 32 + p * 8;
            async_copy16(A  + (size_t)(m0 + rbase + lrow) * K + k0 + lcol,
                         As + rbase * 64);
            async_copy16(Wt + (size_t)(n0 + rbase + lrow) * K + k0 + lcol,
                         Bs + rbase * 64);
        }
        __syncthreads();  // drains vmcnt (global_load_lds) + barrier
#pragma unroll
        for (int ks = 0; ks < 2; ++ks) {
            bf16x8 a[4], b[4];
#pragma unroll
            for (int i = 0; i < 4; ++i) {
                a[i] = *(const bf16x8*)(As + (wm + i * 16 + lm) * 64 + ks * 32 + lq * 8);
                b[i] = *(const bf16x8*)(Bs + (wn + i * 16 + lm) * 64 + ks * 32 + lq * 8);
            }
#pragma unroll
            for (int i = 0; i < 4; ++i)
#pragma unroll
                for (int j = 0; j < 4; ++j)
                    acc[i][j] = __builtin_amdgcn_mfma_f32_16x16x32_bf16(
                        a[i], b[j], acc[i][j], 0, 0, 0);
        }
        __syncthreads();
    }

    // C/D: col = lane&15, row = (lane>>4)*4 + reg
#pragma unroll
    for (int i = 0; i < 4; ++i) {
        const int gm = m0 + wm + i * 16 + lq * 4;
#pragma unroll
        for (int j = 0; j < 4; ++j) {
            const int gn = n0 + wn + j * 16 + lm;
            const float bv = bias ? bias[gn] : 0.f;
#pragma unroll
            for (int r = 0; r < 4; ++r)
                store_v(&C[(size_t)(gm + r) * Nn + gn], acc[i][j][r] + bv);
        }
    }
}

// ---------------------------------------------------------------------------
// MFMA GEMM, register staging (fp32 A): padded LDS, conflict-free.
// ---------------------------------------------------------------------------
template <typename AT, typename CT>
__global__ __launch_bounds__(256) void mfma_gemm(
    const AT* __restrict__ A, const __bf16* __restrict__ Wt,
    const float* __restrict__ bias, CT* __restrict__ C,
    int M, int Nn, int K)
{
    __shared__ __align__(16) __bf16 As[128 * 72];
    __shared__ __align__(16) __bf16 Bs[128 * 72];
    const int tid = threadIdx.x;
    const int m0 = blockIdx.x * 128;
    const int n0 = blockIdx.y * 128;
    const int wave = tid >> 6, lane = tid & 63;
    const int wm = (wave & 1) * 64, wn = (wave >> 1) * 64;
    const int lm = lane & 15, lq = lane >> 4;

    f32x4 acc[4][4] = {};

    const int srow = tid >> 3;
    const int scol = (tid & 7) * 8;

    for (int k0 = 0; k0 < K; k0 += 64) {
#pragma unroll
        for (int p = 0; p < 4; ++p) {
            const int r = srow + 32 * p;
            *(bf16x8*)(As + r * 72 + scol) = ld8(A + (size_t)(m0 + r) * K + k0 + scol);
            *(bf16x8*)(Bs + r * 72 + scol) = *(const bf16x8*)(Wt + (size_t)(n0 + r) * K + k0 + scol);
        }
        __syncthreads();
#pragma unroll
        for (int ks = 0; ks < 2; ++ks) {
            bf16x8 a[4], b[4];
#pragma unroll
            for (int i = 0; i < 4; ++i) {
                a[i] = *(const bf16x8*)(As + (wm + i * 16 + lm) * 72 + ks * 32 + lq * 8);
                b[i] = *(const bf16x8*)(Bs + (wn + i * 16 + lm) * 72 + ks * 32 + lq * 8);
            }
#pragma unroll
            for (int i = 0; i < 4; ++i)
#pragma unroll
                for (int j = 0; j < 4; ++j)
                    acc[i][j] = __builtin_amdgcn_mfma_f32_16x16x32_bf16(
                        a[i], b[j], acc[i][j], 0, 0, 0);
        }
        __syncthreads();
    }

#pragma unroll
    for (int i = 0; i < 4; ++i) {
        const int gm = m0 + wm + i * 16 + lq * 4;
#pragma unroll
        for (int j = 0; j < 4; ++j) {
            const int gn = n0 + wn + j * 16 + lm;
            const float bv = bias ? bias[gn] : 0.f;
#pragma unroll
            for (int r = 0; r < 4; ++r)
                store_v(&C[(size_t)(gm + r) * Nn + gn], acc[i][j][r] + bv);
        }
    }
}

// ---------------------------------------------------------------------------
// Fallback vector GEMM (K=92 aw1, tiny fc head)
// ---------------------------------------------------------------------------
template <typename AT, typename CT>
__global__ __launch_bounds__(256) void gemm_bias(
    const AT* __restrict__ A, const float* __restrict__ W,
    const float* __restrict__ bias, CT* __restrict__ C,
    int M, int Nn, int K)
{
    __shared__ float As[16][65];
    __shared__ float Ws[16][65];
    const int m0 = blockIdx.x * 64;
    const int n0 = blockIdx.y * 64;
    const int tid = threadIdx.x;
    const int tx = tid & 15, ty = tid >> 4;
    float acc[4][4] = {};

    for (int k0 = 0; k0 < K; k0 += 16) {
        {
            const int ar = tid >> 2;
            const int ac = (tid & 3) * 4;
            const int gm = m0 + ar;
#pragma unroll
            for (int j = 0; j < 4; ++j) {
                const int gk = k0 + ac + j;
                float v = 0.f;
                if (gm < M && gk < K) v = to_f(A[(size_t)gm * K + gk]);
                As[ac + j][ar] = v;
            }
        }
        {
            const int wr = tid >> 4;
            const int wc = (tid & 15) * 4;
            const int gk = k0 + wr;
#pragma unroll
            for (int j = 0; j < 4; ++j) {
                float v = 0.f;
                if (gk < K) v = W[(size_t)gk * Nn + n0 + wc + j];
                Ws[wr][wc + j] = v;
            }
        }
        __syncthreads();
#pragma unroll
        for (int kk = 0; kk < 16; ++kk) {
            float a[4], b[4];
#pragma unroll
            for (int i = 0; i < 4; ++i) a[i] = As[kk][ty * 4 + i];
#pragma unroll
            for (int j = 0; j < 4; ++j) b[j] = Ws[kk][tx * 4 + j];
#pragma unroll
            for (int i = 0; i < 4; ++i)
#pragma unroll
                for (int j = 0; j < 4; ++j) acc[i][j] += a[i] * b[j];
        }
        __syncthreads();
    }
#pragma unroll
    for (int i = 0; i < 4; ++i) {
        const int gm = m0 + ty * 4 + i;
        if (gm >= M) continue;
#pragma unroll
        for (int j = 0; j < 4; ++j) {
            const int gn = n0 + tx * 4 + j;
            float v = acc[i][j];
            if (bias) v += bias[gn];
            store_v(&C[(size_t)gm * Nn + gn], v);
        }
    }
}

// ---------------------------------------------------------------------------
// RBF expansion -> bf16.  4 edges per block, 4 cols per thread, packed store.
// ---------------------------------------------------------------------------
__global__ __launch_bounds__(256) void rbf_kernel(
    const float* __restrict__ ea, bf16* __restrict__ rbf)
{
    const int e = blockIdx.x * 4 + (threadIdx.x >> 6);
    const int c0 = (threadIdx.x & 63) * 4;
    const float ax = ea[e * 3 + 0];
    const float ay = ea[e * 3 + 1];
    const float az = ea[e * 3 + 2];
    const float d = sqrtf(ax * ax + ay * ay + az * az);
    const float step = 8.0f / 255.0f;
    const float gamma = 1.0f / (step * step);
    float o[4];
#pragma unroll
    for (int j = 0; j < 4; ++j) {
        const float t = d - (float)(c0 + j) * step;
        o[j] = __expf(-gamma * t * t);
    }
    store_f4(rbf + (size_t)e * DD + c0, make_float4(o[0], o[1], o[2], o[3]));
}

// ---------------------------------------------------------------------------
// Row LayerNorm (+opt SiLU via __expf, +opt fp32 residual). Node-side only.
// 1 row per 64-lane wave (coalesced), 4 rows per block.
// ---------------------------------------------------------------------------
template <typename XT, typename YT>
__global__ __launch_bounds__(256) void ln_act_kernel(
    const XT* __restrict__ X, YT* __restrict__ Y,
    const float* __restrict__ g, const float* __restrict__ b,
    const float* __restrict__ resid, int rows, int do_silu)
{
    const int wave = threadIdx.x >> 6;
    const int lane = threadIdx.x & 63;
    const int r = blockIdx.x * 4 + wave;
    if (r >= rows) return;
    const float4 x = load4(X + (size_t)r * DD + lane * 4);
    float s = x.x + x.y + x.z + x.w;
    float q = x.x * x.x + x.y * x.y + x.z * x.z + x.w * x.w;
    for (int off = 32; off; off >>= 1) {
        s += __shfl_down(s, off);
        q += __shfl_down(q, off);
    }
    s = __shfl(s, 0);
    q = __shfl(q, 0);
    const float mean = s * (1.f / 256.f);
    const float var = q * (1.f / 256.f) - mean * mean;
    const float rs = rsqrtf(var + 1e-5f);
    const int c = lane * 4;
    float xs[4] = {x.x, x.y, x.z, x.w};
    float out[4];
#pragma unroll
    for (int i = 0; i < 4; ++i) {
        float v = (xs[i] - mean) * rs * g[c + i] + b[c + i];
        if (do_silu) v = v / (1.f + __expf(-v));
        out[i] = v;
    }
    if (resid) {
        const float4 rv = load4(resid + (size_t)r * DD + c);
        out[0] += rv.x; out[1] += rv.y; out[2] += rv.z; out[3] += rv.w;
    }
    store_f4(Y + (size_t)r * DD + c, make_float4(out[0], out[1], out[2], out[3]));
}

// ---------------------------------------------------------------------------
// CSR build: histogram, block-scan, fill
// ---------------------------------------------------------------------------
__global__ __launch_bounds__(256) void deg_kernel(
    const int* __restrict__ dst, int* __restrict__ deg)
{
    const int e = blockIdx.x * 256 + threadIdx.x;
    if (e < EE) atomicAdd(&deg[dst[e]], 1);
}

__global__ __launch_bounds__(256) void csr_scan(
    const int* __restrict__ deg, int* __restrict__ rowptr)
{
    __shared__ int part[256];
    const int t = threadIdx.x;
    int local[32];
    int s = 0;
#pragma unroll
    for (int i = 0; i < 32; ++i) { local[i] = deg[t * 32 + i]; s += local[i]; }
    part[t] = s;
    __syncthreads();
    if (t == 0) {
        int run = 0;
        for (int i = 0; i < 256; ++i) { const int v = part[i]; part[i] = run; run += v; }
    }
    __syncthreads();
    int run = part[t];
#pragma unroll
    for (int i = 0; i < 32; ++i) { rowptr[t * 32 + i] = run; run += local[i]; }
    if (t == 255) rowptr[NN] = run;
}

__global__ __launch_bounds__(256) void fill_kernel(
    const int* __restrict__ dst, const int* __restrict__ rowptr,
    int* __restrict__ fill, int* __restrict__ eid)
{
    const int e = blockIdx.x * 256 + threadIdx.x;
    if (e >= EE) return;
    const int d = dst[e];
    const int pos = atomicAdd(&fill[d], 1);
    eid[rowptr[d] + pos] = e;
}

// ---------------------------------------------------------------------------
// Single-pass fused attention (flash-style online softmax), no atomics.
// ---------------------------------------------------------------------------
__global__ __launch_bounds__(256) void attn_kernel(
    const bf16* __restrict__ qkv, const bf16* __restrict__ ee,
    const int* __restrict__ rowptr, const int* __restrict__ eid,
    const int* __restrict__ src, float* __restrict__ msg)
{
    const int n = blockIdx.x;
    const int tid = threadIdx.x;
    const int wave = tid >> 6, lane = tid & 63;
    const int e0 = rowptr[n];
    const int deg = rowptr[n + 1] - e0;

    if (deg == 0) {  // uniform branch
        msg[(size_t)n * DD + tid] = 0.f;
        return;
    }

    __shared__ float wm[4][HH];
    __shared__ float wl[4][HH];
    __shared__ float wacc[4][DD];

    const float4 qreg = load4(qkv + (size_t)n * 768 + lane * 4);

    float m = -3.402823466e38f, l = 0.f;
    float4 acc = {0.f, 0.f, 0.f, 0.f};

    for (int j = wave; j < deg; j += 4) {
        const int e = eid[e0 + j];
        const int s_ = src[e];
        const bf16* srow = qkv + (size_t)s_ * 768;
        const float4 kv = load4(srow + 256 + lane * 4);
        const float4 vv = load4(srow + 512 + lane * 4);
        const float4 ev = load4(ee + (size_t)e * DD + lane * 4);
        float p = qreg.x * (kv.x + ev.x) + qreg.y * (kv.y + ev.y) +
                  qreg.z * (kv.z + ev.z) + qreg.w * (kv.w + ev.w);
        p += __shfl_down(p, 4);
        p += __shfl_down(p, 2);
        p += __shfl_down(p, 1);
        const float s = __shfl(p, lane & 56) * 0.17677669529663687f;
        const float mnew = fmaxf(m, s);
        const float scale = __expf(m - mnew);
        const float pe = __expf(s - mnew);
        l = l * scale + pe;
        acc.x = acc.x * scale + pe * (vv.x + ev.x);
        acc.y = acc.y * scale + pe * (vv.y + ev.y);
        acc.z = acc.z * scale + pe * (vv.z + ev.z);
        acc.w = acc.w * scale + pe * (vv.w + ev.w);
        m = mnew;
    }

    if ((lane & 7) == 0) { wm[wave][lane >> 3] = m; wl[wave][lane >> 3] = l; }
    *(float4*)(&wacc[wave][lane * 4]) = acc;
    __syncthreads();

    {
        const int c = tid, h = tid >> 5;
        float M = wm[0][h];
#pragma unroll
        for (int i = 1; i < 4; ++i) M = fmaxf(M, wm[i][h]);
        float L = 0.f, num = 0.f;
#pragma unroll
        for (int i = 0; i < 4; ++i) {
            const float sc = __expf(wm[i][h] - M);
            L += wl[i][h] * sc;
            num += wacc[i][c] * sc;
        }
        msg[(size_t)n * DD + c] = num / (L + 1e-16f);
    }
}

__global__ __launch_bounds__(256) void zero_kernel(float* __restrict__ p, int n)
{
    const int i = blockIdx.x * 256 + threadIdx.x;
    if (i < n) p[i] = 0.f;
}

__global__ __launch_bounds__(256) void pool_kernel(
    const float* __restrict__ node, const int* __restrict__ batch,
    float* __restrict__ sums, float* __restrict__ cnt)
{
    const int n = blockIdx.x;
    const int c = threadIdx.x;
    const int b = batch[n];
    atomicAdd(&sums[b * DD + c], node[(size_t)n * DD + c]);
    if (c == 0) atomicAdd(&cnt[b], 1.0f);
}

__global__ __launch_bounds__(256) void pooled_kernel(
    const float* __restrict__ sums, const float* __restrict__ cnt,
    float* __restrict__ pooled)
{
    const int b = blockIdx.x;
    const int c = threadIdx.x;
    float cc = cnt[b];
    if (cc < 1.f) cc = 1.f;
    pooled[b * DD + c] = sums[b * DD + c] / cc;
}

__global__ __launch_bounds__(64) void final_kernel(
    const float* __restrict__ fc, const float* __restrict__ fow,
    const float* __restrict__ fob, float* __restrict__ out)
{
    const int b = blockIdx.x;
    const int lane = threadIdx.x;
    float s = 0.f;
#pragma unroll
    for (int i = lane; i < FCD; i += 64) s += fc[(size_t)b * FCD + i] * fow[i];
    for (int off = 32; off; off >>= 1) s += __shfl_down(s, off);
    if (lane == 0) out[b] = s + fob[0];
}

// ---------------------------------------------------------------------------
extern "C" void kernel_launch(void* const* d_in, const int* in_sizes, int n_in,
                              void* d_out, int out_size, void* d_ws,
                              size_t ws_size, hipStream_t stream)
{
    const float* x         = (const float*)d_in[0];
    const float* edge_attr = (const float*)d_in[1];
    const int*   eidx      = (const int*)d_in[2];
    const int*   batch     = (const int*)d_in[3];
    const float* aw1 = (const float*)d_in[4];
    const float* ab1 = (const float*)d_in[5];
    const float* ag1 = (const float*)d_in[6];
    const float* abt1 = (const float*)d_in[7];
    const float* aw2 = (const float*)d_in[8];
    const float* ab2 = (const float*)d_in[9];
    const float* rw1 = (const float*)d_in[10];
    const float* rb1 = (const float*)d_in[11];
    const float* rg1 = (const float*)d_in[12];
    const float* rbt1 = (const float*)d_in[13];
    const float* rw2 = (const float*)d_in[14];
    const float* rb2 = (const float*)d_in[15];
    const float* rg2 = (const float*)d_in[16];
    const float* rbt2 = (const float*)d_in[17];
    const float* rw3 = (const float*)d_in[18];
    const float* rb3 = (const float*)d_in[19];
    const float* Wq = (const float*)d_in[20];
    const float* bq = (const float*)d_in[21];
    const float* Wk = (const float*)d_in[22];
    const float* bk = (const float*)d_in[23];
    const float* Wv = (const float*)d_in[24];
    const float* bv = (const float*)d_in[25];
    const float* We_ = (const float*)d_in[26];
    const float* be_ = (const float*)d_in[27];
    const float* Wo = (const float*)d_in[28];
    const float* bo = (const float*)d_in[29];
    const float* lng = (const float*)d_in[30];
    const float* lnb = (const float*)d_in[31];
    const float* fw1 = (const float*)d_in[32];
    const float* fb1 = (const float*)d_in[33];
    const float* fow = (const float*)d_in[34];
    const float* fob = (const float*)d_in[35];

    const int* src = eidx;
    const int* dst = eidx + EE;

    // workspace carve-up (~170 MB)
    char* w = (char*)d_ws;
    size_t off = 0;
    auto alloc = [&](size_t bytes) -> void* {
        void* p = w + off;
        off += (bytes + 255) & ~(size_t)255;
        return p;
    };
    bf16* e_buf = (bf16*)alloc((size_t)EE * DD * 2);   // 64 MB
    bf16* t_buf = (bf16*)alloc((size_t)EE * DD * 2);   // 64 MB
    float* node = (float*)alloc((size_t)NN * DD * 4);  // 8 MB
    bf16*  qkv  = (bf16*)alloc((size_t)NN * 768 * 2);  // 12 MB
    float* msg  = (float*)alloc((size_t)NN * DD * 4);  // 8 MB
    float* outb = (float*)alloc((size_t)NN * DD * 4);  // 8 MB
    int* deg    = (int*)alloc((size_t)NN * 4);         // | contiguous zero
    int* fillc  = (int*)alloc((size_t)NN * 4);         // | region (deg+fill)
    int* rowptr = (int*)alloc((size_t)(NN + 1) * 4);
    int* eid    = (int*)alloc((size_t)EE * 4);         // 512 KB
    float* sums  = (float*)alloc((size_t)BB * DD * 4); // | contiguous with cnt
    float* cnt   = (float*)alloc((size_t)BB * 4);      // |
    float* pooled = (float*)alloc((size_t)BB * DD * 4);
    float* fc    = (float*)alloc((size_t)BB * FCD * 4);
    __bf16* Wt  = (__bf16*)alloc((size_t)34 * 65536 * 2);  // 4.25 MB
    float* qkvb = (float*)alloc((size_t)LL * 768 * 4);     // 18 KB
    (void)ws_size; (void)n_in; (void)in_sizes; (void)out_size;

    const dim3 blk(256);
    auto WT = [&](int i) -> const __bf16* { return Wt + (size_t)i * 65536; };

    // ---- one-time prep: weight transposes, bias pack, CSR ----
    hipLaunchKernelGGL(transpose_weights, dim3(16, 34), blk, 0, stream,
                       rw1, rw2, rw3, aw2, Wq, Wk, Wv, We_, Wo, Wt);
    hipLaunchKernelGGL(pack_qkv_bias, dim3((LL * 768 + 255) / 256), blk, 0, stream, bq, bk, bv, qkvb);
    hipLaunchKernelGGL(zero_kernel, dim3((2 * NN + 255) / 256), blk, 0, stream, (float*)deg, 2 * NN);
    hipLaunchKernelGGL(deg_kernel, dim3(EE / 256), blk, 0, stream, dst, deg);
    hipLaunchKernelGGL(csr_scan, dim3(1), blk, 0, stream, deg, rowptr);
    hipLaunchKernelGGL(fill_kernel, dim3(EE / 256), blk, 0, stream, dst, rowptr, fillc, eid);

    // ---- edge MLP: rbf -> [GEMM+LN+SiLU] -> [GEMM+LN+SiLU] -> GEMM ----
    const dim3 geM(EE / 128, DD / 128);
    hipLaunchKernelGGL(rbf_kernel, dim3(EE / 4), blk, 0, stream, edge_attr, t_buf);
    hipLaunchKernelGGL(mfma_gemm_ln, dim3(EE / 128), blk, 0, stream, t_buf, WT(0), rb1, rg1, rbt1, e_buf, EE, 1);
    hipLaunchKernelGGL(mfma_gemm_ln, dim3(EE / 128), blk, 0, stream, e_buf, WT(1), rb2, rg2, rbt2, t_buf, EE, 1);
    hipLaunchKernelGGL((mfma_gemm_async<bf16>), geM, blk, 0, stream, t_buf, WT(2), rb3, e_buf, EE, DD, DD);

    // ---- atom embedding: x@aw1 -> LN+SiLU -> @aw2 ----
    {
        dim3 gn64(NN / 64, DD / 64);
        hipLaunchKernelGGL((gemm_bias<float, float>), gn64, blk, 0, stream, x, aw1, ab1, outb, NN, DD, F_AT);
        hipLaunchKernelGGL((ln_act_kernel<float, float>), dim3(NN / 4), blk, 0, stream, outb, outb, ag1, abt1, (const float*)nullptr, NN, 1);
        hipLaunchKernelGGL((mfma_gemm<float, float>), dim3(NN / 128, DD / 128), blk, 0, stream, outb, WT(3), ab2, node, NN, DD, DD);
    }

    // ---- L attention layers ----
    for (int l = 0; l < LL; ++l) {
        const size_t bo_ = (size_t)l * DD;
        hipLaunchKernelGGL((mfma_gemm<float, bf16>), dim3(NN / 128, 768 / 128), blk, 0, stream,
                           node, WT(4 + 5 * l), qkvb + (size_t)l * 768, qkv, NN, 768, DD);
        hipLaunchKernelGGL((mfma_gemm_async<bf16>), geM, blk, 0, stream, e_buf, WT(7 + 5 * l), be_ + bo_, t_buf, EE, DD, DD);
        hipLaunchKernelGGL(attn_kernel, dim3(NN), blk, 0, stream, qkv, t_buf, rowptr, eid, src, msg);
        hipLaunchKernelGGL((mfma_gemm<float, float>), dim3(NN / 128, DD / 128), blk, 0, stream, msg, WT(8 + 5 * l), bo + bo_, outb, NN, DD, DD);
        hipLaunchKernelGGL((ln_act_kernel<float, float>), dim3(NN / 4), blk, 0, stream, outb, node, lng + bo_, lnb + bo_, node, NN, 0);
    }

    // ---- pooling + FC head ----
    const int PZ = BB * DD + BB;
    hipLaunchKernelGGL(zero_kernel, dim3((PZ + 255) / 256), blk, 0, stream, sums, PZ);
    hipLaunchKernelGGL(pool_kernel, dim3(NN), blk, 0, stream, node, batch, sums, cnt);
    hipLaunchKernelGGL(pooled_kernel, dim3(BB), blk, 0, stream, sums, cnt, pooled);
    {
        dim3 gf(BB / 64, FCD / 64);
        hipLaunchKernelGGL((gemm_bias<float, float>), gf, blk, 0, stream, pooled, fw1, fb1, fc, BB, FCD, DD);
    }
    hipLaunchKernelGGL(final_kernel, dim3(BB), dim3(64), 0, stream, fc, fow, fob, (float*)d_out);
}

// Round 10
// 1122.944 us; speedup vs baseline: 1.2408x; 1.0451x over previous
//
#include <hip/hip_runtime.h>
#include <hip/hip_bf16.h>
#include <cstddef>

// Problem constants (Prdnet_3324304687823)
#define NN    8192
#define EE    131072
#define BB    256
#define F_AT  92
#define DD    256
#define HH    8
#define HDIM  32
#define LL    6
#define FCD   512

typedef __hip_bfloat16 bf16;
typedef __attribute__((ext_vector_type(8))) __bf16 bf16x8;
typedef __attribute__((ext_vector_type(4))) float f32x4;

__device__ __forceinline__ float to_f(float x) { return x; }
__device__ __forceinline__ float to_f(bf16 x) { return __bfloat162float(x); }
__device__ __forceinline__ float bfu(unsigned short u) {
    return __uint_as_float(((unsigned)u) << 16);
}
__device__ __forceinline__ unsigned short bfbits(float x) {
    bf16 h = __float2bfloat16(x);
    return *(unsigned short*)&h;
}
__device__ __forceinline__ void store_v(float* p, float v) { *p = v; }
__device__ __forceinline__ void store_v(bf16* p, float v) { *p = __float2bfloat16(v); }

__device__ __forceinline__ float4 load4(const float* p) { return *(const float4*)p; }
__device__ __forceinline__ float4 load4(const bf16* p) {
    const ushort4 r = *(const ushort4*)p;
    return make_float4(bfu(r.x), bfu(r.y), bfu(r.z), bfu(r.w));
}

__device__ __forceinline__ void store_f4(float* p, const float4& f) {
    *(float4*)p = f;
}
__device__ __forceinline__ void store_f4(bf16* p, const float4& f) {
    ushort4 u = {bfbits(f.x), bfbits(f.y), bfbits(f.z), bfbits(f.w)};
    *(ushort4*)p = u;
}

__device__ __forceinline__ bf16x8 ld8(const bf16* p) { return *(const bf16x8*)p; }
__device__ __forceinline__ bf16x8 ld8(const float* p) {
    const float4 f0 = *(const float4*)p;
    const float4 f1 = *(const float4*)(p + 4);
    bf16x8 r;
    r[0] = (__bf16)f0.x; r[1] = (__bf16)f0.y; r[2] = (__bf16)f0.z; r[3] = (__bf16)f0.w;
    r[4] = (__bf16)f1.x; r[5] = (__bf16)f1.y; r[6] = (__bf16)f1.z; r[7] = (__bf16)f1.w;
    return r;
}

// async global->LDS, 16 B per lane; LDS dest = wave-uniform base + lane*16
__device__ __forceinline__ void async_copy16(const void* g, void* l) {
    __builtin_amdgcn_global_load_lds(
        (const __attribute__((address_space(1))) unsigned int*)g,
        (__attribute__((address_space(3))) unsigned int*)l, 16, 0, 0);
}

// ---------------------------------------------------------------------------
// Batched weight transpose: out[midx][n][k] = (bf16) src[midx][k][n]
// midx: 0=rw1 1=rw2 2=rw3 3=aw2, then per layer l: 4+5l+{0:q,1:k,2:v,3:e,4:o}
// Slots 34..39 are the combined rw3@We weights (filled by combine_w3e).
// ---------------------------------------------------------------------------
__global__ __launch_bounds__(256) void transpose_weights(
    const float* __restrict__ rw1, const float* __restrict__ rw2,
    const float* __restrict__ rw3, const float* __restrict__ aw2,
    const float* __restrict__ Wq, const float* __restrict__ Wk,
    const float* __restrict__ Wv, const float* __restrict__ We,
    const float* __restrict__ Wo, __bf16* __restrict__ out)
{
    __shared__ float tile[64][65];
    const int midx = blockIdx.y;
    const float* src;
    if (midx == 0) src = rw1;
    else if (midx == 1) src = rw2;
    else if (midx == 2) src = rw3;
    else if (midx == 3) src = aw2;
    else {
        const int l = (midx - 4) / 5, s = (midx - 4) % 5;
        const float* bases[5] = {Wq, Wk, Wv, We, Wo};
        src = bases[s] + (size_t)l * 65536;
    }
    __bf16* dst = out + (size_t)midx * 65536;
    const int k0 = (blockIdx.x >> 2) * 64;
    const int n0 = (blockIdx.x & 3) * 64;
    const int c = threadIdx.x & 63;
    const int r0 = threadIdx.x >> 6;
#pragma unroll
    for (int p = 0; p < 16; ++p) {
        const int r = r0 + p * 4;
        tile[r][c] = src[(size_t)(k0 + r) * 256 + n0 + c];
    }
    __syncthreads();
#pragma unroll
    for (int p = 0; p < 16; ++p) {
        const int n = r0 + p * 4;
        dst[(size_t)(n0 + n) * 256 + k0 + c] = (__bf16)tile[c][n];
    }
}

// pack per-layer [bq|bk|bv] -> qkvb[l*768 + ...]
__global__ __launch_bounds__(256) void pack_qkv_bias(
    const float* __restrict__ bq, const float* __restrict__ bk,
    const float* __restrict__ bv, float* __restrict__ out)
{
    const int i = blockIdx.x * 256 + threadIdx.x;
    if (i >= LL * 768) return;
    const int l = i / 768, r = i % 768;
    const float* s = (r < 256) ? bq : (r < 512) ? bk : bv;
    out[i] = s[l * 256 + (r & 255)];
}

// ---------------------------------------------------------------------------
// combine_w3e: Wt_out[l][n][k] = bf16( sum_m rw3[k][m] * We[l][m][n] )
// Folds edge-MLP layer 3 into the per-layer We. 64x64 tile per block,
// grid (4,4,LL). fp32 accumulate, one bf16 rounding.
// ---------------------------------------------------------------------------
__global__ __launch_bounds__(256) void combine_w3e(
    const float* __restrict__ rw3, const float* __restrict__ We,
    __bf16* __restrict__ Wt_out)
{
    __shared__ float As[16][65];
    __shared__ float Ws[16][65];
    const int l = blockIdx.z;
    const float* W = We + (size_t)l * 65536;
    __bf16* dst = Wt_out + (size_t)l * 65536;
    const int m0 = blockIdx.x * 64;   // k index of combined weight
    const int n0 = blockIdx.y * 64;
    const int tid = threadIdx.x;
    const int tx = tid & 15, ty = tid >> 4;
    float acc[4][4] = {};

    for (int k0 = 0; k0 < 256; k0 += 16) {
        {
            const int ar = tid >> 2;
            const int ac = (tid & 3) * 4;
#pragma unroll
            for (int j = 0; j < 4; ++j)
                As[ac + j][ar] = rw3[(size_t)(m0 + ar) * 256 + k0 + ac + j];
        }
        {
            const int wr = tid >> 4;
            const int wc = (tid & 15) * 4;
#pragma unroll
            for (int j = 0; j < 4; ++j)
                Ws[wr][wc + j] = W[(size_t)(k0 + wr) * 256 + n0 + wc + j];
        }
        __syncthreads();
#pragma unroll
        for (int kk = 0; kk < 16; ++kk) {
            float a[4], b[4];
#pragma unroll
            for (int i = 0; i < 4; ++i) a[i] = As[kk][ty * 4 + i];
#pragma unroll
            for (int j = 0; j < 4; ++j) b[j] = Ws[kk][tx * 4 + j];
#pragma unroll
            for (int i = 0; i < 4; ++i)
#pragma unroll
                for (int j = 0; j < 4; ++j) acc[i][j] += a[i] * b[j];
        }
        __syncthreads();
    }
#pragma unroll
    for (int i = 0; i < 4; ++i) {
        const int gk = m0 + ty * 4 + i;
#pragma unroll
        for (int j = 0; j < 4; ++j) {
            const int gn = n0 + tx * 4 + j;
            dst[(size_t)gn * 256 + gk] = (__bf16)acc[i][j];  // transposed store
        }
    }
}

// be_c[l][n] = sum_m rb3[m] * We[l][m][n] + be[l][n]
__global__ __launch_bounds__(256) void combine_bias(
    const float* __restrict__ rb3, const float* __restrict__ We,
    const float* __restrict__ be, float* __restrict__ out)
{
    const int l = blockIdx.x;
    const int n = threadIdx.x;
    const float* W = We + (size_t)l * 65536;
    float s = be[l * 256 + n];
    for (int m = 0; m < 256; ++m) s += rb3[m] * W[m * 256 + n];
    out[l * 256 + n] = s;
}

// ---------------------------------------------------------------------------
// Fused MFMA GEMM + LayerNorm + SiLU: C = silu(LN(A@W + bias)), Nn=K=256.
// 64x256 tile: each wave owns 16 full rows -> LN stats via 16-lane shfl_xor,
// no inter-wave merge. acc = 16 frags (64 VGPR). LDS 40 KB (As 8K + Bs 32K).
// grid = M/64 (2048 blocks at E). A bf16 async-staged; output bf16.
// ---------------------------------------------------------------------------
__global__ __launch_bounds__(256) void mfma_gemm_ln(
    const bf16* __restrict__ A, const __bf16* __restrict__ Wt,
    const float* __restrict__ bias, const float* __restrict__ g,
    const float* __restrict__ b, bf16* __restrict__ C, int do_silu)
{
    __shared__ __align__(16) __bf16 As[64 * 64];
    __shared__ __align__(16) __bf16 Bs[256 * 64];
    const int tid = threadIdx.x;
    const int m0 = blockIdx.x * 64;
    const int wave = tid >> 6, lane = tid & 63;
    const int lm = lane & 15, lq = lane >> 4;
    const int lrow = lane >> 3, lcol = (lane & 7) * 8;

    f32x4 acc[16] = {};

    for (int k0 = 0; k0 < 256; k0 += 64) {
#pragma unroll
        for (int p = 0; p < 2; ++p) {
            const int rbase = wave * 16 + p * 8;
            async_copy16(A + (size_t)(m0 + rbase + lrow) * 256 + k0 + lcol,
                         As + rbase * 64);
        }
#pragma unroll
        for (int p = 0; p < 8; ++p) {
            const int rbase = wave * 64 + p * 8;
            async_copy16(Wt + (size_t)(rbase + lrow) * 256 + k0 + lcol,
                         Bs + rbase * 64);
        }
        __syncthreads();
#pragma unroll
        for (int ks = 0; ks < 2; ++ks) {
            const bf16x8 a = *(const bf16x8*)(As + (wave * 16 + lm) * 64 + ks * 32 + lq * 8);
#pragma unroll
            for (int j = 0; j < 16; ++j) {
                const bf16x8 bf = *(const bf16x8*)(Bs + (j * 16 + lm) * 64 + ks * 32 + lq * 8);
                acc[j] = __builtin_amdgcn_mfma_f32_16x16x32_bf16(a, bf, acc[j], 0, 0, 0);
            }
        }
        __syncthreads();
    }

    float gg[16], bb[16];
#pragma unroll
    for (int j = 0; j < 16; ++j) {
        const float bv = bias[j * 16 + lm];
        gg[j] = g[j * 16 + lm];
        bb[j] = b[j * 16 + lm];
#pragma unroll
        for (int r = 0; r < 4; ++r) acc[j][r] += bv;
    }

    // each lane holds 4 rows (lq*4+r) x 16 cols (j*16+lm); lanes sharing a row
    // differ only in low-4 bits -> shfl_xor reduce over lm
#pragma unroll
    for (int r = 0; r < 4; ++r) {
        float s = 0.f, q = 0.f;
#pragma unroll
        for (int j = 0; j < 16; ++j) { const float v = acc[j][r]; s += v; q += v * v; }
#pragma unroll
        for (int msk = 1; msk < 16; msk <<= 1) {
            s += __shfl_xor(s, msk);
            q += __shfl_xor(q, msk);
        }
        const float mean = s * (1.f / 256.f);
        const float var = q * (1.f / 256.f) - mean * mean;
        const float rs = rsqrtf(var + 1e-5f);
        bf16* crow = C + (size_t)(m0 + wave * 16 + lq * 4 + r) * 256;
#pragma unroll
        for (int j = 0; j < 16; ++j) {
            float v = (acc[j][r] - mean) * rs * gg[j] + bb[j];
            if (do_silu) v = v / (1.f + __expf(-v));
            crow[j * 16 + lm] = __float2bfloat16(v);
        }
    }
}

// ---------------------------------------------------------------------------
// MFMA GEMM, async staging (A bf16): C = A@W + bias, Wt[Nn][K] bf16.
// 128x128 tile, BK=64, 4 waves 2x2.
// ---------------------------------------------------------------------------
template <typename CT>
__global__ __launch_bounds__(256) void mfma_gemm_async(
    const bf16* __restrict__ A, const __bf16* __restrict__ Wt,
    const float* __restrict__ bias, CT* __restrict__ C,
    int M, int Nn, int K)
{
    __shared__ __align__(16) __bf16 As[128 * 64];
    __shared__ __align__(16) __bf16 Bs[128 * 64];
    const int tid = threadIdx.x;
    const int m0 = blockIdx.x * 128;
    const int n0 = blockIdx.y * 128;
    const int wave = tid >> 6, lane = tid & 63;
    const int wm = (wave & 1) * 64, wn = (wave >> 1) * 64;
    const int lm = lane & 15, lq = lane >> 4;
    const int lrow = lane >> 3;
    const int lcol = (lane & 7) * 8;

    f32x4 acc[4][4] = {};

    for (int k0 = 0; k0 < K; k0 += 64) {
#pragma unroll
        for (int p = 0; p < 4; ++p) {
            const int rbase = wave * 32 + p * 8;
            async_copy16(A  + (size_t)(m0 + rbase + lrow) * K + k0 + lcol,
                         As + rbase * 64);
            async_copy16(Wt + (size_t)(n0 + rbase + lrow) * K + k0 + lcol,
                         Bs + rbase * 64);
        }
        __syncthreads();
#pragma unroll
        for (int ks = 0; ks < 2; ++ks) {
            bf16x8 a[4], b[4];
#pragma unroll
            for (int i = 0; i < 4; ++i) {
                a[i] = *(const bf16x8*)(As + (wm + i * 16 + lm) * 64 + ks * 32 + lq * 8);
                b[i] = *(const bf16x8*)(Bs + (wn + i * 16 + lm) * 64 + ks * 32 + lq * 8);
            }
#pragma unroll
            for (int i = 0; i < 4; ++i)
#pragma unroll
                for (int j = 0; j < 4; ++j)
                    acc[i][j] = __builtin_amdgcn_mfma_f32_16x16x32_bf16(
                        a[i], b[j], acc[i][j], 0, 0, 0);
        }
        __syncthreads();
    }

#pragma unroll
    for (int i = 0; i < 4; ++i) {
        const int gm = m0 + wm + i * 16 + lq * 4;
#pragma unroll
        for (int j = 0; j < 4; ++j) {
            const int gn = n0 + wn + j * 16 + lm;
            const float bv = bias ? bias[gn] : 0.f;
#pragma unroll
            for (int r = 0; r < 4; ++r)
                store_v(&C[(size_t)(gm + r) * Nn + gn], acc[i][j][r] + bv);
        }
    }
}

// ---------------------------------------------------------------------------
// MFMA GEMM, register staging (fp32 A): padded LDS, conflict-free.
// ---------------------------------------------------------------------------
template <typename AT, typename CT>
__global__ __launch_bounds__(256) void mfma_gemm(
    const AT* __restrict__ A, const __bf16* __restrict__ Wt,
    const float* __restrict__ bias, CT* __restrict__ C,
    int M, int Nn, int K)
{
    __shared__ __align__(16) __bf16 As[128 * 72];
    __shared__ __align__(16) __bf16 Bs[128 * 72];
    const int tid = threadIdx.x;
    const int m0 = blockIdx.x * 128;
    const int n0 = blockIdx.y * 128;
    const int wave = tid >> 6, lane = tid & 63;
    const int wm = (wave & 1) * 64, wn = (wave >> 1) * 64;
    const int lm = lane & 15, lq = lane >> 4;

    f32x4 acc[4][4] = {};

    const int srow = tid >> 3;
    const int scol = (tid & 7) * 8;

    for (int k0 = 0; k0 < K; k0 += 64) {
#pragma unroll
        for (int p = 0; p < 4; ++p) {
            const int r = srow + 32 * p;
            *(bf16x8*)(As + r * 72 + scol) = ld8(A + (size_t)(m0 + r) * K + k0 + scol);
            *(bf16x8*)(Bs + r * 72 + scol) = *(const bf16x8*)(Wt + (size_t)(n0 + r) * K + k0 + scol);
        }
        __syncthreads();
#pragma unroll
        for (int ks = 0; ks < 2; ++ks) {
            bf16x8 a[4], b[4];
#pragma unroll
            for (int i = 0; i < 4; ++i) {
                a[i] = *(const bf16x8*)(As + (wm + i * 16 + lm) * 72 + ks * 32 + lq * 8);
                b[i] = *(const bf16x8*)(Bs + (wn + i * 16 + lm) * 72 + ks * 32 + lq * 8);
            }
#pragma unroll
            for (int i = 0; i < 4; ++i)
#pragma unroll
                for (int j = 0; j < 4; ++j)
                    acc[i][j] = __builtin_amdgcn_mfma_f32_16x16x32_bf16(
                        a[i], b[j], acc[i][j], 0, 0, 0);
        }
        __syncthreads();
    }

#pragma unroll
    for (int i = 0; i < 4; ++i) {
        const int gm = m0 + wm + i * 16 + lq * 4;
#pragma unroll
        for (int j = 0; j < 4; ++j) {
            const int gn = n0 + wn + j * 16 + lm;
            const float bv = bias ? bias[gn] : 0.f;
#pragma unroll
            for (int r = 0; r < 4; ++r)
                store_v(&C[(size_t)(gm + r) * Nn + gn], acc[i][j][r] + bv);
        }
    }
}

// ---------------------------------------------------------------------------
// Fallback vector GEMM (K=92 aw1, tiny fc head)
// ---------------------------------------------------------------------------
template <typename AT, typename CT>
__global__ __launch_bounds__(256) void gemm_bias(
    const AT* __restrict__ A, const float* __restrict__ W,
    const float* __restrict__ bias, CT* __restrict__ C,
    int M, int Nn, int K)
{
    __shared__ float As[16][65];
    __shared__ float Ws[16][65];
    const int m0 = blockIdx.x * 64;
    const int n0 = blockIdx.y * 64;
    const int tid = threadIdx.x;
    const int tx = tid & 15, ty = tid >> 4;
    float acc[4][4] = {};

    for (int k0 = 0; k0 < K; k0 += 16) {
        {
            const int ar = tid >> 2;
            const int ac = (tid & 3) * 4;
            const int gm = m0 + ar;
#pragma unroll
            for (int j = 0; j < 4; ++j) {
                const int gk = k0 + ac + j;
                float v = 0.f;
                if (gm < M && gk < K) v = to_f(A[(size_t)gm * K + gk]);
                As[ac + j][ar] = v;
            }
        }
        {
            const int wr = tid >> 4;
            const int wc = (tid & 15) * 4;
            const int gk = k0 + wr;
#pragma unroll
            for (int j = 0; j < 4; ++j) {
                float v = 0.f;
                if (gk < K) v = W[(size_t)gk * Nn + n0 + wc + j];
                Ws[wr][wc + j] = v;
            }
        }
        __syncthreads();
#pragma unroll
        for (int kk = 0; kk < 16; ++kk) {
            float a[4], b[4];
#pragma unroll
            for (int i = 0; i < 4; ++i) a[i] = As[kk][ty * 4 + i];
#pragma unroll
            for (int j = 0; j < 4; ++j) b[j] = Ws[kk][tx * 4 + j];
#pragma unroll
            for (int i = 0; i < 4; ++i)
#pragma unroll
                for (int j = 0; j < 4; ++j) acc[i][j] += a[i] * b[j];
        }
        __syncthreads();
    }
#pragma unroll
    for (int i = 0; i < 4; ++i) {
        const int gm = m0 + ty * 4 + i;
        if (gm >= M) continue;
#pragma unroll
        for (int j = 0; j < 4; ++j) {
            const int gn = n0 + tx * 4 + j;
            float v = acc[i][j];
            if (bias) v += bias[gn];
            store_v(&C[(size_t)gm * Nn + gn], v);
        }
    }
}

// ---------------------------------------------------------------------------
// RBF expansion -> bf16.  4 edges per block, 4 cols per thread, packed store.
// ---------------------------------------------------------------------------
__global__ __launch_bounds__(256) void rbf_kernel(
    const float* __restrict__ ea, bf16* __restrict__ rbf)
{
    const int e = blockIdx.x * 4 + (threadIdx.x >> 6);
    const int c0 = (threadIdx.x & 63) * 4;
    const float ax = ea[e * 3 + 0];
    const float ay = ea[e * 3 + 1];
    const float az = ea[e * 3 + 2];
    const float d = sqrtf(ax * ax + ay * ay + az * az);
    const float step = 8.0f / 255.0f;
    const float gamma = 1.0f / (step * step);
    float o[4];
#pragma unroll
    for (int j = 0; j < 4; ++j) {
        const float t = d - (float)(c0 + j) * step;
        o[j] = __expf(-gamma * t * t);
    }
    store_f4(rbf + (size_t)e * DD + c0, make_float4(o[0], o[1], o[2], o[3]));
}

// ---------------------------------------------------------------------------
// Row LayerNorm (+opt SiLU via __expf, +opt fp32 residual). Node-side only.
// 1 row per 64-lane wave (coalesced), 4 rows per block.
// ---------------------------------------------------------------------------
template <typename XT, typename YT>
__global__ __launch_bounds__(256) void ln_act_kernel(
    const XT* __restrict__ X, YT* __restrict__ Y,
    const float* __restrict__ g, const float* __restrict__ b,
    const float* __restrict__ resid, int rows, int do_silu)
{
    const int wave = threadIdx.x >> 6;
    const int lane = threadIdx.x & 63;
    const int r = blockIdx.x * 4 + wave;
    if (r >= rows) return;
    const float4 x = load4(X + (size_t)r * DD + lane * 4);
    float s = x.x + x.y + x.z + x.w;
    float q = x.x * x.x + x.y * x.y + x.z * x.z + x.w * x.w;
    for (int off = 32; off; off >>= 1) {
        s += __shfl_down(s, off);
        q += __shfl_down(q, off);
    }
    s = __shfl(s, 0);
    q = __shfl(q, 0);
    const float mean = s * (1.f / 256.f);
    const float var = q * (1.f / 256.f) - mean * mean;
    const float rs = rsqrtf(var + 1e-5f);
    const int c = lane * 4;
    float xs[4] = {x.x, x.y, x.z, x.w};
    float out[4];
#pragma unroll
    for (int i = 0; i < 4; ++i) {
        float v = (xs[i] - mean) * rs * g[c + i] + b[c + i];
        if (do_silu) v = v / (1.f + __expf(-v));
        out[i] = v;
    }
    if (resid) {
        const float4 rv = load4(resid + (size_t)r * DD + c);
        out[0] += rv.x; out[1] += rv.y; out[2] += rv.z; out[3] += rv.w;
    }
    store_f4(Y + (size_t)r * DD + c, make_float4(out[0], out[1], out[2], out[3]));
}

// ---------------------------------------------------------------------------
// CSR build: histogram, block-scan, fill
// ---------------------------------------------------------------------------
__global__ __launch_bounds__(256) void deg_kernel(
    const int* __restrict__ dst, int* __restrict__ deg)
{
    const int e = blockIdx.x * 256 + threadIdx.x;
    if (e < EE) atomicAdd(&deg[dst[e]], 1);
}

__global__ __launch_bounds__(256) void csr_scan(
    const int* __restrict__ deg, int* __restrict__ rowptr)
{
    __shared__ int part[256];
    const int t = threadIdx.x;
    int local[32];
    int s = 0;
#pragma unroll
    for (int i = 0; i < 32; ++i) { local[i] = deg[t * 32 + i]; s += local[i]; }
    part[t] = s;
    __syncthreads();
    if (t == 0) {
        int run = 0;
        for (int i = 0; i < 256; ++i) { const int v = part[i]; part[i] = run; run += v; }
    }
    __syncthreads();
    int run = part[t];
#pragma unroll
    for (int i = 0; i < 32; ++i) { rowptr[t * 32 + i] = run; run += local[i]; }
    if (t == 255) rowptr[NN] = run;
}

__global__ __launch_bounds__(256) void fill_kernel(
    const int* __restrict__ dst, const int* __restrict__ rowptr,
    int* __restrict__ fill, int* __restrict__ eid)
{
    const int e = blockIdx.x * 256 + threadIdx.x;
    if (e >= EE) return;
    const int d = dst[e];
    const int pos = atomicAdd(&fill[d], 1);
    eid[rowptr[d] + pos] = e;
}

// ---------------------------------------------------------------------------
// Single-pass fused attention (flash-style online softmax), no atomics.
// ---------------------------------------------------------------------------
__global__ __launch_bounds__(256) void attn_kernel(
    const bf16* __restrict__ qkv, const bf16* __restrict__ ee,
    const int* __restrict__ rowptr, const int* __restrict__ eid,
    const int* __restrict__ src, float* __restrict__ msg)
{
    const int n = blockIdx.x;
    const int tid = threadIdx.x;
    const int wave = tid >> 6, lane = tid & 63;
    const int e0 = rowptr[n];
    const int deg = rowptr[n + 1] - e0;

    if (deg == 0) {  // uniform branch
        msg[(size_t)n * DD + tid] = 0.f;
        return;
    }

    __shared__ float wm[4][HH];
    __shared__ float wl[4][HH];
    __shared__ float wacc[4][DD];

    const float4 qreg = load4(qkv + (size_t)n * 768 + lane * 4);

    float m = -3.402823466e38f, l = 0.f;
    float4 acc = {0.f, 0.f, 0.f, 0.f};

    for (int j = wave; j < deg; j += 4) {
        const int e = eid[e0 + j];
        const int s_ = src[e];
        const bf16* srow = qkv + (size_t)s_ * 768;
        const float4 kv = load4(srow + 256 + lane * 4);
        const float4 vv = load4(srow + 512 + lane * 4);
        const float4 ev = load4(ee + (size_t)e * DD + lane * 4);
        float p = qreg.x * (kv.x + ev.x) + qreg.y * (kv.y + ev.y) +
                  qreg.z * (kv.z + ev.z) + qreg.w * (kv.w + ev.w);
        p += __shfl_down(p, 4);
        p += __shfl_down(p, 2);
        p += __shfl_down(p, 1);
        const float s = __shfl(p, lane & 56) * 0.17677669529663687f;
        const float mnew = fmaxf(m, s);
        const float scale = __expf(m - mnew);
        const float pe = __expf(s - mnew);
        l = l * scale + pe;
        acc.x = acc.x * scale + pe * (vv.x + ev.x);
        acc.y = acc.y * scale + pe * (vv.y + ev.y);
        acc.z = acc.z * scale + pe * (vv.z + ev.z);
        acc.w = acc.w * scale + pe * (vv.w + ev.w);
        m = mnew;
    }

    if ((lane & 7) == 0) { wm[wave][lane >> 3] = m; wl[wave][lane >> 3] = l; }
    *(float4*)(&wacc[wave][lane * 4]) = acc;
    __syncthreads();

    {
        const int c = tid, h = tid >> 5;
        float M = wm[0][h];
#pragma unroll
        for (int i = 1; i < 4; ++i) M = fmaxf(M, wm[i][h]);
        float L = 0.f, num = 0.f;
#pragma unroll
        for (int i = 0; i < 4; ++i) {
            const float sc = __expf(wm[i][h] - M);
            L += wl[i][h] * sc;
            num += wacc[i][c] * sc;
        }
        msg[(size_t)n * DD + c] = num / (L + 1e-16f);
    }
}

__global__ __launch_bounds__(256) void zero_kernel(float* __restrict__ p, int n)
{
    const int i = blockIdx.x * 256 + threadIdx.x;
    if (i < n) p[i] = 0.f;
}

__global__ __launch_bounds__(256) void pool_kernel(
    const float* __restrict__ node, const int* __restrict__ batch,
    float* __restrict__ sums, float* __restrict__ cnt)
{
    const int n = blockIdx.x;
    const int c = threadIdx.x;
    const int b = batch[n];
    atomicAdd(&sums[b * DD + c], node[(size_t)n * DD + c]);
    if (c == 0) atomicAdd(&cnt[b], 1.0f);
}

__global__ __launch_bounds__(256) void pooled_kernel(
    const float* __restrict__ sums, const float* __restrict__ cnt,
    float* __restrict__ pooled)
{
    const int b = blockIdx.x;
    const int c = threadIdx.x;
    float cc = cnt[b];
    if (cc < 1.f) cc = 1.f;
    pooled[b * DD + c] = sums[b * DD + c] / cc;
}

__global__ __launch_bounds__(64) void final_kernel(
    const float* __restrict__ fc, const float* __restrict__ fow,
    const float* __restrict__ fob, float* __restrict__ out)
{
    const int b = blockIdx.x;
    const int lane = threadIdx.x;
    float s = 0.f;
#pragma unroll
    for (int i = lane; i < FCD; i += 64) s += fc[(size_t)b * FCD + i] * fow[i];
    for (int off = 32; off; off >>= 1) s += __shfl_down(s, off);
    if (lane == 0) out[b] = s + fob[0];
}

// ---------------------------------------------------------------------------
extern "C" void kernel_launch(void* const* d_in, const int* in_sizes, int n_in,
                              void* d_out, int out_size, void* d_ws,
                              size_t ws_size, hipStream_t stream)
{
    const float* x         = (const float*)d_in[0];
    const float* edge_attr = (const float*)d_in[1];
    const int*   eidx      = (const int*)d_in[2];
    const int*   batch     = (const int*)d_in[3];
    const float* aw1 = (const float*)d_in[4];
    const float* ab1 = (const float*)d_in[5];
    const float* ag1 = (const float*)d_in[6];
    const float* abt1 = (const float*)d_in[7];
    const float* aw2 = (const float*)d_in[8];
    const float* ab2 = (const float*)d_in[9];
    const float* rw1 = (const float*)d_in[10];
    const float* rb1 = (const float*)d_in[11];
    const float* rg1 = (const float*)d_in[12];
    const float* rbt1 = (const float*)d_in[13];
    const float* rw2 = (const float*)d_in[14];
    const float* rb2 = (const float*)d_in[15];
    const float* rg2 = (const float*)d_in[16];
    const float* rbt2 = (const float*)d_in[17];
    const float* rw3 = (const float*)d_in[18];
    const float* rb3 = (const float*)d_in[19];
    const float* Wq = (const float*)d_in[20];
    const float* bq = (const float*)d_in[21];
    const float* Wk = (const float*)d_in[22];
    const float* bk = (const float*)d_in[23];
    const float* Wv = (const float*)d_in[24];
    const float* bv = (const float*)d_in[25];
    const float* We_ = (const float*)d_in[26];
    const float* be_ = (const float*)d_in[27];
    const float* Wo = (const float*)d_in[28];
    const float* bo = (const float*)d_in[29];
    const float* lng = (const float*)d_in[30];
    const float* lnb = (const float*)d_in[31];
    const float* fw1 = (const float*)d_in[32];
    const float* fb1 = (const float*)d_in[33];
    const float* fow = (const float*)d_in[34];
    const float* fob = (const float*)d_in[35];

    const int* src = eidx;
    const int* dst = eidx + EE;

    // workspace carve-up (~170 MB)
    char* w = (char*)d_ws;
    size_t off = 0;
    auto alloc = [&](size_t bytes) -> void* {
        void* p = w + off;
        off += (bytes + 255) & ~(size_t)255;
        return p;
    };
    bf16* t_buf = (bf16*)alloc((size_t)EE * DD * 2);   // 64 MB — persistent edge
    bf16* e_buf = (bf16*)alloc((size_t)EE * DD * 2);   // 64 MB — MLP ping / ee
    float* node = (float*)alloc((size_t)NN * DD * 4);  // 8 MB
    bf16*  qkv  = (bf16*)alloc((size_t)NN * 768 * 2);  // 12 MB
    float* msg  = (float*)alloc((size_t)NN * DD * 4);  // 8 MB
    float* outb = (float*)alloc((size_t)NN * DD * 4);  // 8 MB
    int* deg    = (int*)alloc((size_t)NN * 4);         // | contiguous zero
    int* fillc  = (int*)alloc((size_t)NN * 4);         // | region (deg+fill)
    int* rowptr = (int*)alloc((size_t)(NN + 1) * 4);
    int* eid    = (int*)alloc((size_t)EE * 4);         // 512 KB
    float* sums  = (float*)alloc((size_t)BB * DD * 4); // | contiguous with cnt
    float* cnt   = (float*)alloc((size_t)BB * 4);      // |
    float* pooled = (float*)alloc((size_t)BB * DD * 4);
    float* fc    = (float*)alloc((size_t)BB * FCD * 4);
    __bf16* Wt  = (__bf16*)alloc((size_t)40 * 65536 * 2);  // 5.25 MB (34 + 6 combined)
    float* qkvb = (float*)alloc((size_t)LL * 768 * 4);     // 18 KB
    float* be_c = (float*)alloc((size_t)LL * 256 * 4);     // 6 KB — combined ee bias
    (void)ws_size; (void)n_in; (void)in_sizes; (void)out_size;

    const dim3 blk(256);
    auto WT = [&](int i) -> const __bf16* { return Wt + (size_t)i * 65536; };

    // ---- one-time prep: transposes, combined rw3@We, bias pack, CSR ----
    hipLaunchKernelGGL(transpose_weights, dim3(16, 34), blk, 0, stream,
                       rw1, rw2, rw3, aw2, Wq, Wk, Wv, We_, Wo, Wt);
    hipLaunchKernelGGL(combine_w3e, dim3(4, 4, LL), blk, 0, stream, rw3, We_, Wt + (size_t)34 * 65536);
    hipLaunchKernelGGL(combine_bias, dim3(LL), blk, 0, stream, rb3, We_, be_, be_c);
    hipLaunchKernelGGL(pack_qkv_bias, dim3((LL * 768 + 255) / 256), blk, 0, stream, bq, bk, bv, qkvb);
    hipLaunchKernelGGL(zero_kernel, dim3((2 * NN + 255) / 256), blk, 0, stream, (float*)deg, 2 * NN);
    hipLaunchKernelGGL(deg_kernel, dim3(EE / 256), blk, 0, stream, dst, deg);
    hipLaunchKernelGGL(csr_scan, dim3(1), blk, 0, stream, deg, rowptr);
    hipLaunchKernelGGL(fill_kernel, dim3(EE / 256), blk, 0, stream, dst, rowptr, fillc, eid);

    // ---- edge MLP: rbf -> [GEMM+LN+SiLU] -> [GEMM+LN+SiLU]; rw3 folded into We ----
    hipLaunchKernelGGL(rbf_kernel, dim3(EE / 4), blk, 0, stream, edge_attr, t_buf);
    hipLaunchKernelGGL(mfma_gemm_ln, dim3(EE / 64), blk, 0, stream, t_buf, WT(0), rb1, rg1, rbt1, e_buf, 1);
    hipLaunchKernelGGL(mfma_gemm_ln, dim3(EE / 64), blk, 0, stream, e_buf, WT(1), rb2, rg2, rbt2, t_buf, 1);
    // t_buf now holds the persistent edge features (pre-rw3)

    // ---- atom embedding: x@aw1 -> LN+SiLU -> @aw2 ----
    {
        dim3 gn64(NN / 64, DD / 64);
        hipLaunchKernelGGL((gemm_bias<float, float>), gn64, blk, 0, stream, x, aw1, ab1, outb, NN, DD, F_AT);
        hipLaunchKernelGGL((ln_act_kernel<float, float>), dim3(NN / 4), blk, 0, stream, outb, outb, ag1, abt1, (const float*)nullptr, NN, 1);
        hipLaunchKernelGGL((mfma_gemm<float, float>), dim3(NN / 128, DD / 128), blk, 0, stream, outb, WT(3), ab2, node, NN, DD, DD);
    }

    // ---- L attention layers ----
    const dim3 geM(EE / 128, DD / 128);
    for (int l = 0; l < LL; ++l) {
        const size_t bo_ = (size_t)l * DD;
        hipLaunchKernelGGL((mfma_gemm<float, bf16>), dim3(NN / 128, 768 / 128), blk, 0, stream,
                           node, WT(4 + 5 * l), qkvb + (size_t)l * 768, qkv, NN, 768, DD);
        // ee = t_buf @ (rw3@We_l) + (rb3@We_l + be_l)
        hipLaunchKernelGGL((mfma_gemm_async<bf16>), geM, blk, 0, stream, t_buf, WT(34 + l), be_c + (size_t)l * 256, e_buf, EE, DD, DD);
        hipLaunchKernelGGL(attn_kernel, dim3(NN), blk, 0, stream, qkv, e_buf, rowptr, eid, src, msg);
        hipLaunchKernelGGL((mfma_gemm<float, float>), dim3(NN / 128, DD / 128), blk, 0, stream, msg, WT(8 + 5 * l), bo + bo_, outb, NN, DD, DD);
        hipLaunchKernelGGL((ln_act_kernel<float, float>), dim3(NN / 4), blk, 0, stream, outb, node, lng + bo_, lnb + bo_, node, NN, 0);
    }

    // ---- pooling + FC head ----
    const int PZ = BB * DD + BB;
    hipLaunchKernelGGL(zero_kernel, dim3((PZ + 255) / 256), blk, 0, stream, sums, PZ);
    hipLaunchKernelGGL(pool_kernel, dim3(NN), blk, 0, stream, node, batch, sums, cnt);
    hipLaunchKernelGGL(pooled_kernel, dim3(BB), blk, 0, stream, sums, cnt, pooled);
    {
        dim3 gf(BB / 64, FCD / 64);
        hipLaunchKernelGGL((gemm_bias<float, float>), gf, blk, 0, stream, pooled, fw1, fb1, fc, BB, FCD, DD);
    }
    hipLaunchKernelGGL(final_kernel, dim3(BB), dim3(64), 0, stream, fc, fow, fob, (float*)d_out);
}